// Round 2
// baseline (585.052 us; speedup 1.0000x reference)
//
#include <hip/hip_runtime.h>
#include <stdint.h>

// Multi_LSTMs: bidirectional 4-head LSTM, BS=8 NT=128 CH=1024 H=512 G=2048.
// R1-R4: poison-poll state exchange, no fences in step loop (see history).
// R5: recurrence MFMA accumulation split into 2 independent chains.
// R6 (this round): FUSE ih-GEMM into the recurrence launch. Blocks 0..127 run
//   the persistent recurrence; blocks 128..1151 run m97-style GEMM tiles in
//   "production waves" p=0..7 (fwd mt=p, bwd mt=7-p) matching consumption
//   order. Recurrence polls ihg against f32-NaN poison (R4 pattern); GEMM
//   C-writes are agent-scope relaxed atomic stores (write-through). This
//   hides the ~150us GEMM behind the 94%-idle recurrence.
//   Workspace flattened to overlay-free 128 MB (all buffers live concurrently).

typedef __attribute__((ext_vector_type(8))) short short8;
typedef __attribute__((ext_vector_type(4))) float floatx4;
typedef unsigned long long ull;

#define POISON 0x7FC07FC07FC07FC0ull   // 4 x bf16 NaN (stateS)
#define POISON_F32 0x7FC00000u         // f32 NaN (ihg)
#define POISON_F32X2 0x7FC000007FC00000ull

#define GLOAD_LDS16(g, l)                                        \
  __builtin_amdgcn_global_load_lds(                              \
      (const __attribute__((address_space(1))) void*)(g),        \
      (__attribute__((address_space(3))) void*)(l), 16, 0, 0)

__device__ __forceinline__ unsigned short f2bf(float f) {
  unsigned u = __float_as_uint(f);
  u = (u + 0x7fffu + ((u >> 16) & 1u)) >> 16;  // RNE
  return (unsigned short)u;
}
__device__ __forceinline__ float sigm(float x) { return 1.0f / (1.0f + __expf(-x)); }
__device__ __forceinline__ float tanh_f(float x) {
  float ax = fabsf(x);
  float e = __expf(-2.0f * ax);
  float t = (1.0f - e) / (1.0f + e);
  return x < 0.0f ? -t : t;
}

// x[8][128][1024][4] f32 -> Xp[4][1024][1024] bf16, row m = t*8+b
__global__ void pack_x_k(const float* __restrict__ x, unsigned short* __restrict__ Xp) {
  int g = blockIdx.x * 256 + threadIdx.x;
  int m = g >> 10, c = g & 1023;
  int t = m >> 3, b = m & 7;
  float4 v = *(const float4*)(x + ((size_t)((b * 128 + t) * 1024 + c)) * 4);
  Xp[g]           = f2bf(v.x);
  Xp[1048576 + g] = f2bf(v.y);
  Xp[2097152 + g] = f2bf(v.z);
  Xp[3145728 + g] = f2bf(v.w);
}

__global__ void cast_bf_k(const float* __restrict__ src, unsigned short* __restrict__ dst, int n4) {
  int i = blockIdx.x * 256 + threadIdx.x;
  if (i >= n4) return;
  float4 v = ((const float4*)src)[i];
  ushort4 o;
  o.x = f2bf(v.x); o.y = f2bf(v.y); o.z = f2bf(v.z); o.w = f2bf(v.w);
  ((ushort4*)dst)[i] = o;
}

__global__ void fill_u64_k(ull* __restrict__ p, ull v) {
  p[(size_t)blockIdx.x * 256 + threadIdx.x] = v;
}

// Poll 8 ih gate values (2 ni x 4 r, b=quad*4+r<8) against f32-NaN poison.
// Agent-scope relaxed atomic loads (bypass stale caches). base is thread's
// ih + ((grp*1024 + t*8)*2048) + (w*512 + j0 + lo); ni adds 16, b adds 2048.
__device__ __forceinline__ void poll_ih(const float* base, int quad, float ihv[2][4]) {
  unsigned v[2][4];
  bool ready;
  do {
    ready = true;
#pragma unroll
    for (int ni = 0; ni < 2; ++ni)
#pragma unroll
      for (int r = 0; r < 4; ++r) {
        int b = quad * 4 + r;
        if (b < 8) {
          v[ni][r] = __hip_atomic_load((const unsigned*)base + ni * 16 + (size_t)b * 2048,
                                       __ATOMIC_RELAXED, __HIP_MEMORY_SCOPE_AGENT);
          if (v[ni][r] == POISON_F32) ready = false;
        } else {
          v[ni][r] = 0u;
        }
      }
    if (!ready) __builtin_amdgcn_s_sleep(2);
  } while (!ready);
#pragma unroll
  for (int ni = 0; ni < 2; ++ni)
#pragma unroll
    for (int r = 0; r < 4; ++r) ihv[ni][r] = __uint_as_float(v[ni][r]);
}

// Fused kernel. grid = 1152.
//  bid <  128: persistent recurrence (grp = bid&7 -> same-XCD groups).
//  bid >= 128: GEMM tile q=bid-128: dk=q&7 (XCD-matched), ntl=(q>>3)&15,
//              production wave p=q>>7, mt = (dk<4) ? p : 7-p.
__global__ __launch_bounds__(256) void fused_k(
    const unsigned short* __restrict__ Xp, const unsigned short* __restrict__ Wihb,
    const float* __restrict__ bihf, const float* __restrict__ bhhf,
    const float* __restrict__ bihb, const float* __restrict__ bhhb,
    float* __restrict__ ih, const unsigned short* __restrict__ whh,
    float* __restrict__ out, ull* __restrict__ stateS) {
  __shared__ __align__(16) char smem[20992];  // union: rec 20736B / gemm 16384B
  const int bid = blockIdx.x;
  const int tid = threadIdx.x;
  const int L = tid & 63;
  const int wv = tid >> 6;
  const int quad = L >> 4, lo = L & 15;

  if (bid >= 128) {
    // ---------------- GEMM path (m97 structure, 128x128 tile, BK=32) --------
    const int q = bid - 128;
    const int dk = q & 7, ntl = (q >> 3) & 15, p = q >> 7;
    const int mt = (dk < 4) ? p : (7 - p);
    const int kh = dk & 3;
    const int wm = wv & 1, wn = wv >> 1;

    unsigned short* As = (unsigned short*)smem;          // 128*32 shorts = 8KB
    unsigned short* Bs = (unsigned short*)(smem + 8192); // 8KB

    const unsigned short* Ab = Xp + (size_t)kh * 1048576 + (size_t)mt * 128 * 1024;
    const unsigned short* Bb = Wihb + (size_t)dk * 2097152 + (size_t)ntl * 128 * 1024;

    floatx4 acc[4][4] = {};

    for (int kc = 0; kc < 32; ++kc) {
#pragma unroll
      for (int ph = 0; ph < 2; ++ph) {
        int c = ph * 256 + wv * 64 + L;       // 16B chunk id, 0..511
        int ldsb = (ph * 256 + wv * 64) * 8;  // wave-uniform base (shorts)
        GLOAD_LDS16(Ab + (size_t)(c >> 2) * 1024 + kc * 32 + (c & 3) * 8, As + ldsb);
        GLOAD_LDS16(Bb + (size_t)(c >> 2) * 1024 + kc * 32 + (c & 3) * 8, Bs + ldsb);
      }
      __syncthreads();  // implicit vmcnt(0): LDS tiles ready
      short8 af[4], bf[4];
#pragma unroll
      for (int mi = 0; mi < 4; ++mi)
        af[mi] = *(const short8*)(As + (wm * 64 + mi * 16 + lo) * 32 + quad * 8);
#pragma unroll
      for (int ni = 0; ni < 4; ++ni)
        bf[ni] = *(const short8*)(Bs + (wn * 64 + ni * 16 + lo) * 32 + quad * 8);
#pragma unroll
      for (int mi = 0; mi < 4; ++mi)
#pragma unroll
        for (int ni = 0; ni < 4; ++ni)
          acc[mi][ni] = __builtin_amdgcn_mfma_f32_16x16x32_bf16(af[mi], bf[ni], acc[mi][ni], 0, 0, 0);
      __syncthreads();  // LDS reads done before next stage
    }

    const float* bihp = (dk < 4) ? bihf : bihb;
    const float* bhhp = (dk < 4) ? bhhf : bhhb;
#pragma unroll
    for (int ni = 0; ni < 4; ++ni) {
      int g = ntl * 128 + wn * 64 + ni * 16 + lo;
      float bv = bihp[kh * 2048 + g] + bhhp[kh * 2048 + g];
#pragma unroll
      for (int mi = 0; mi < 4; ++mi)
#pragma unroll
        for (int r = 0; r < 4; ++r) {
          int m = mt * 128 + wm * 64 + mi * 16 + quad * 4 + r;
          // agent-scope write-through so poison-pollers see it at the
          // coherence point (plain stores could linger in this XCD's L2)
          __hip_atomic_store(&ih[((size_t)dk * 1024 + m) * 2048 + g], acc[mi][ni][r] + bv,
                             __ATOMIC_RELAXED, __HIP_MEMORY_SCOPE_AGENT);
        }
    }
    return;
  }

  // ---------------- recurrence path (persistent, poison-polled) ------------
  const int grp = bid & 7;
  const int d = grp >> 2, kh = grp & 3;
  const int wg = bid >> 3;
  const int j0 = wg * 32;

  unsigned short* h_lds = (unsigned short*)smem;   // 16*520 shorts = 16640B
  float* gbuf = (float*)(smem + 16640);            // [4][8][32] = 4096B

  for (int i = tid; i < 16 * 520; i += 256) h_lds[i] = 0;

  // Whh slice -> register B-frags: wave wv=gate, rows g = wv*512 + j0 + ni*16 + lo
  short8 bfrag[2][16];
#pragma unroll
  for (int ni = 0; ni < 2; ++ni) {
    const unsigned short* wb =
        whh + ((size_t)grp * 2048 + (size_t)(wv * 512 + j0 + ni * 16 + lo)) * 512 + quad * 8;
#pragma unroll
    for (int kk = 0; kk < 16; ++kk) bfrag[ni][kk] = *(const short8*)(wb + kk * 32);
  }

  const int pb = tid >> 5, pjj = tid & 31;  // pointwise cell (b, jj)
  float creg = 0.0f;

  // prefetch + poll ih gates for s=0 (GEMM production wave 0)
  float ihv[2][4];
  {
    int t0 = d ? 127 : 0;
    const float* base =
        ih + ((size_t)grp * 1024 + (size_t)t0 * 8) * 2048 + (wv * 512 + j0 + lo);
    poll_ih(base, quad, ihv);
  }

  const int srow = tid >> 5;         // batch row 0..7
  const int scol = (tid & 31) * 16;  // h-col base within row (elements)

  for (int s = 0; s < 128; ++s) {
    const int t = d ? (127 - s) : s;

    if (s) {  // stage h_prev: poll slot s until this thread's producers wrote it
      const ull* src = stateS + ((size_t)grp * 128 + s) * 1024 + tid * 4;
      ull v0, v1, v2, v3;
      do {
        v0 = __hip_atomic_load(src + 0, __ATOMIC_RELAXED, __HIP_MEMORY_SCOPE_AGENT);
        v1 = __hip_atomic_load(src + 1, __ATOMIC_RELAXED, __HIP_MEMORY_SCOPE_AGENT);
        v2 = __hip_atomic_load(src + 2, __ATOMIC_RELAXED, __HIP_MEMORY_SCOPE_AGENT);
        v3 = __hip_atomic_load(src + 3, __ATOMIC_RELAXED, __HIP_MEMORY_SCOPE_AGENT);
      } while (v0 == POISON || v1 == POISON || v2 == POISON || v3 == POISON);
      unsigned short* dl = h_lds + srow * 520 + scol;
      *(ull*)(dl + 0) = v0;
      *(ull*)(dl + 4) = v1;
      *(ull*)(dl + 8) = v2;
      *(ull*)(dl + 12) = v3;
    }
    __syncthreads();

    floatx4 acc[2] = {};
    floatx4 acc2[2] = {};
    {  // A[m][k]: m = L&15 (batch, rows 8..15 zero); 2 independent chains
      const unsigned short* ar = h_lds + lo * 520 + quad * 8;
#pragma unroll
      for (int kk = 0; kk < 16; kk += 2) {
        short8 a0 = *(const short8*)(ar + kk * 32);
        short8 a1 = *(const short8*)(ar + (kk + 1) * 32);
#pragma unroll
        for (int ni = 0; ni < 2; ++ni) {
          acc[ni]  = __builtin_amdgcn_mfma_f32_16x16x32_bf16(a0, bfrag[ni][kk], acc[ni], 0, 0, 0);
          acc2[ni] = __builtin_amdgcn_mfma_f32_16x16x32_bf16(a1, bfrag[ni][kk + 1], acc2[ni], 0, 0, 0);
        }
      }
    }
#pragma unroll
    for (int ni = 0; ni < 2; ++ni)
#pragma unroll
      for (int r = 0; r < 4; ++r) {
        int b = quad * 4 + r;
        if (b < 8) gbuf[((wv * 8) + b) * 32 + ni * 16 + lo] = acc[ni][r] + acc2[ni][r] + ihv[ni][r];
      }
    __syncthreads();

    // pointwise LSTM cell: one (b, jj) per thread
    {
      float ig = gbuf[(0 * 8 + pb) * 32 + pjj], fg = gbuf[(1 * 8 + pb) * 32 + pjj];
      float gg = gbuf[(2 * 8 + pb) * 32 + pjj], og = gbuf[(3 * 8 + pb) * 32 + pjj];
      float cn = sigm(fg) * creg + sigm(ig) * tanh_f(gg);
      creg = cn;
      float h = sigm(og) * tanh_f(cn);

      if (s < 127) {  // publish h into slot s+1: shfl-pack 4 lanes -> 8B store
        unsigned hs = f2bf(h);
        int base = L & ~3;
        unsigned v0 = __shfl(hs, base + 0);
        unsigned v1 = __shfl(hs, base + 1);
        unsigned v2 = __shfl(hs, base + 2);
        unsigned v3 = __shfl(hs, base + 3);
        if ((L & 3) == 0) {
          ull wvv = (ull)v0 | ((ull)v1 << 16) | ((ull)v2 << 32) | ((ull)v3 << 48);
          ull* dst = stateS + ((size_t)grp * 128 + (s + 1)) * 1024 + pb * 128 + ((j0 + pjj) >> 2);
          __hip_atomic_store(dst, wvv, __ATOMIC_RELAXED, __HIP_MEMORY_SCOPE_AGENT);
        }
      }
      out[(((size_t)pb * 128 + t) * 1024 + d * 512 + j0 + pjj) * 4 + kh] = h;
    }

    if (s < 127) {  // prefetch+poll ih for s+1 AFTER publish (off critical path)
      int tn = d ? (126 - s) : (s + 1);
      const float* base =
          ih + ((size_t)grp * 1024 + (size_t)tn * 8) * 2048 + (wv * 512 + j0 + lo);
      poll_ih(base, quad, ihv);
    }
  }
}

extern "C" void kernel_launch(void* const* d_in, const int* in_sizes, int n_in,
                              void* d_out, int out_size, void* d_ws, size_t ws_size,
                              hipStream_t stream) {
  (void)in_sizes; (void)n_in; (void)out_size; (void)ws_size;
  const float* x     = (const float*)d_in[0];
  const float* Wih_f = (const float*)d_in[1];
  const float* Whh_f = (const float*)d_in[2];
  const float* bih_f = (const float*)d_in[3];
  const float* bhh_f = (const float*)d_in[4];
  const float* Wih_b = (const float*)d_in[5];
  const float* Whh_b = (const float*)d_in[6];
  const float* bih_b = (const float*)d_in[7];
  const float* bhh_b = (const float*)d_in[8];
  float* out = (float*)d_out;
  char* ws = (char*)d_ws;

  // Overlay-free layout (all buffers live concurrently in fused kernel): 128 MB
  ull* stateS          = (ull*)ws;                               // 8 MB
  float* ihg           = (float*)(ws + (8ull << 20));            // 64 MB
  unsigned short* Xp   = (unsigned short*)(ws + (72ull << 20));  // 8 MB
  unsigned short* Wihb = (unsigned short*)(ws + (80ull << 20));  // 32 MB
  unsigned short* Whhb = (unsigned short*)(ws + (112ull << 20)); // 16 MB

  pack_x_k<<<4096, 256, 0, stream>>>(x, Xp);
  cast_bf_k<<<8192, 256, 0, stream>>>(Wih_f, Wihb, 2097152);
  cast_bf_k<<<8192, 256, 0, stream>>>(Wih_b, Wihb + 8388608, 2097152);
  cast_bf_k<<<4096, 256, 0, stream>>>(Whh_f, Whhb, 1048576);
  cast_bf_k<<<4096, 256, 0, stream>>>(Whh_b, Whhb + 4194304, 1048576);
  fill_u64_k<<<4096, 256, 0, stream>>>(stateS, POISON);
  fill_u64_k<<<32768, 256, 0, stream>>>((ull*)ihg, POISON_F32X2);
  fused_k<<<1152, 256, 0, stream>>>(Xp, Wihb, bih_f, bhh_f, bih_b, bhh_b,
                                    ihg, Whhb, out, stateS);
}

// Round 3
// 552.841 us; speedup vs baseline: 1.0583x; 1.0583x over previous
//
#include <hip/hip_runtime.h>
#include <stdint.h>

// Multi_LSTMs: bidirectional 4-head LSTM, BS=8 NT=128 CH=1024 H=512 G=2048.
// R1-R4: poison-poll state exchange, no fences in step loop.
// R5: recurrence MFMA accumulation split into 2 independent chains.
// R6 FAILED: GEMM/recurrence fusion — blocking ih poll + contention (+98us). Reverted.
// R7 (this round):
//   a) __launch_bounds__(256,1) on recurrence: round-1 VGPR_Count=100 proves the
//      128-VGPR Whh bfrag was NOT register-resident (reloaded from L2 per step,
//      latency-exposed on the serial chain). 1 WG/CU -> allow 512 VGPRs.
//   b) gate-paired B-tiles (tile0={i,f}, tile1={g,o} split on lane lo<8/>=8):
//      pointwise via 2x shfl_xor(8) -> no gbuf, ONE barrier/step, earlier publish.
//      h_lds double-buffered (single-barrier safety by program order).
//   c) prep_k merges pack_x + 4 casts + poison fill; bias folded into GEMM epilogue.
//   d) bid remap: kh-quads of same (d,wg) share an XCD -> out 4B-lane writes merge
//      to full 64B lines in L2.
//   e) s_sleep(1) on failed poll iterations.

typedef __attribute__((ext_vector_type(8))) short short8;
typedef __attribute__((ext_vector_type(4))) float floatx4;
typedef unsigned long long ull;

#define POISON 0x7FC07FC07FC07FC0ull  // 4 x bf16 NaN (stateS)

#define GLOAD_LDS16(g, l)                                        \
  __builtin_amdgcn_global_load_lds(                              \
      (const __attribute__((address_space(1))) void*)(g),        \
      (__attribute__((address_space(3))) void*)(l), 16, 0, 0)

__device__ __forceinline__ unsigned short f2bf(float f) {
  unsigned u = __float_as_uint(f);
  u = (u + 0x7fffu + ((u >> 16) & 1u)) >> 16;  // RNE
  return (unsigned short)u;
}
__device__ __forceinline__ float sigm(float x) { return 1.0f / (1.0f + __expf(-x)); }
__device__ __forceinline__ float tanh_f(float x) {
  float ax = fabsf(x);
  float e = __expf(-2.0f * ax);
  float t = (1.0f - e) / (1.0f + e);
  return x < 0.0f ? -t : t;
}

// One prep kernel: pack x, cast Wih_f/Wih_b/Whh_f/Whh_b to bf16, poison stateS.
// grid = 32768 x 256 = 8,388,608 work items.
__global__ __launch_bounds__(256) void prep_k(
    const float* __restrict__ x,
    const float* __restrict__ Wih_f, const float* __restrict__ Wih_b,
    const float* __restrict__ Whh_f, const float* __restrict__ Whh_b,
    unsigned short* __restrict__ Xp, unsigned short* __restrict__ Wihb,
    unsigned short* __restrict__ Whhb, ull* __restrict__ stateS) {
  size_t i = (size_t)blockIdx.x * 256 + threadIdx.x;
  if (i < 1048576) {  // pack x: x[8][128][1024][4] f32 -> Xp[4][1024][1024] bf16
    int g = (int)i;
    int m = g >> 10, c = g & 1023;
    int t = m >> 3, b = m & 7;
    float4 v = *(const float4*)(x + ((size_t)((b * 128 + t) * 1024 + c)) * 4);
    Xp[g]           = f2bf(v.x);
    Xp[1048576 + g] = f2bf(v.y);
    Xp[2097152 + g] = f2bf(v.z);
    Xp[3145728 + g] = f2bf(v.w);
  } else if (i < 3145728) {  // Wih_f: 2M float4
    size_t j = i - 1048576;
    float4 v = ((const float4*)Wih_f)[j];
    ushort4 o;
    o.x = f2bf(v.x); o.y = f2bf(v.y); o.z = f2bf(v.z); o.w = f2bf(v.w);
    ((ushort4*)Wihb)[j] = o;
  } else if (i < 5242880) {  // Wih_b
    size_t j = i - 3145728;
    float4 v = ((const float4*)Wih_b)[j];
    ushort4 o;
    o.x = f2bf(v.x); o.y = f2bf(v.y); o.z = f2bf(v.z); o.w = f2bf(v.w);
    ((ushort4*)Wihb)[2097152 + j] = o;
  } else if (i < 6291456) {  // Whh_f: 1M float4
    size_t j = i - 5242880;
    float4 v = ((const float4*)Whh_f)[j];
    ushort4 o;
    o.x = f2bf(v.x); o.y = f2bf(v.y); o.z = f2bf(v.z); o.w = f2bf(v.w);
    ((ushort4*)Whhb)[j] = o;
  } else if (i < 7340032) {  // Whh_b
    size_t j = i - 6291456;
    float4 v = ((const float4*)Whh_b)[j];
    ushort4 o;
    o.x = f2bf(v.x); o.y = f2bf(v.y); o.z = f2bf(v.z); o.w = f2bf(v.w);
    ((ushort4*)Whhb)[1048576 + j] = o;
  } else {  // stateS poison: 1M ull
    stateS[i - 7340032] = POISON;
  }
}

// ih[dk][m][g] = sum_c Xp[kh][m][c] * Wb[dk][g][c] + bih[g] + bhh[g]
// m97 structure: 128x128 tile, BK=32, global_load_lds(16B), 4 waves 2x2.
__global__ __launch_bounds__(256) void gemm_ih_k(
    const unsigned short* __restrict__ Xp, const unsigned short* __restrict__ Wb,
    const float* __restrict__ bihf, const float* __restrict__ bhhf,
    const float* __restrict__ bihb, const float* __restrict__ bhhb,
    float* __restrict__ ih) {
  const int mt = blockIdx.x, ntl = blockIdx.y, dk = blockIdx.z;
  const int kh = dk & 3;
  const int tid = threadIdx.x;
  const int L = tid & 63, w = tid >> 6;
  const int wm = w & 1, wn = w >> 1;
  const int quad = L >> 4, lo = L & 15;

  __shared__ unsigned short As[128 * 32];  // 8 KB, no pad (glds contiguity)
  __shared__ unsigned short Bs[128 * 32];

  const unsigned short* Ab = Xp + (size_t)kh * 1048576 + (size_t)mt * 128 * 1024;
  const unsigned short* Bb = Wb + (size_t)dk * 2097152 + (size_t)ntl * 128 * 1024;

  floatx4 acc[4][4] = {};

  for (int kc = 0; kc < 32; ++kc) {
#pragma unroll
    for (int q = 0; q < 2; ++q) {
      int c = q * 256 + w * 64 + L;       // 16B chunk id, 0..511
      int ldsb = (q * 256 + w * 64) * 8;  // wave-uniform base (shorts)
      GLOAD_LDS16(Ab + (size_t)(c >> 2) * 1024 + kc * 32 + (c & 3) * 8, As + ldsb);
      GLOAD_LDS16(Bb + (size_t)(c >> 2) * 1024 + kc * 32 + (c & 3) * 8, Bs + ldsb);
    }
    __syncthreads();  // implicit vmcnt(0): LDS tiles ready
    short8 af[4], bf[4];
#pragma unroll
    for (int mi = 0; mi < 4; ++mi)
      af[mi] = *(const short8*)(As + (wm * 64 + mi * 16 + lo) * 32 + quad * 8);
#pragma unroll
    for (int ni = 0; ni < 4; ++ni)
      bf[ni] = *(const short8*)(Bs + (wn * 64 + ni * 16 + lo) * 32 + quad * 8);
#pragma unroll
    for (int mi = 0; mi < 4; ++mi)
#pragma unroll
      for (int ni = 0; ni < 4; ++ni)
        acc[mi][ni] = __builtin_amdgcn_mfma_f32_16x16x32_bf16(af[mi], bf[ni], acc[mi][ni], 0, 0, 0);
    __syncthreads();  // LDS reads done before next stage
  }

  const float* bihp = (dk < 4) ? bihf : bihb;
  const float* bhhp = (dk < 4) ? bhhf : bhhb;
#pragma unroll
  for (int ni = 0; ni < 4; ++ni) {
    int g = ntl * 128 + wn * 64 + ni * 16 + lo;
    float bv = bihp[kh * 2048 + g] + bhhp[kh * 2048 + g];
#pragma unroll
    for (int mi = 0; mi < 4; ++mi)
#pragma unroll
      for (int r = 0; r < 4; ++r) {
        int m = mt * 128 + wm * 64 + mi * 16 + quad * 4 + r;
        ih[((size_t)dk * 1024 + m) * 2048 + g] = acc[mi][ni][r] + bv;
      }
  }
}

// Persistent recurrence. grid=128. bid remap: kh=bid>>5, d=(bid>>4)&1, wg=bid&15
// -> same-(d,wg) kh-quads co-located on one XCD (out-line merge in L2).
// Wave wv owns h-cols [j0+wv*8, +8) x ALL 4 gates:
//   tile0: lanes lo<8 gate i, lo>=8 gate f; tile1: lo<8 gate g, lo>=8 gate o.
// Pointwise: 2x shfl_xor(8) brings the partner gate pair; each (b,col) computed
// redundantly by lanes lo and lo+8 (identical f32 ops -> identical creg).
__global__ __launch_bounds__(256, 1) void lstm_rec_k(
    const float* __restrict__ ih, const unsigned short* __restrict__ whh,
    float* __restrict__ out, ull* __restrict__ stateS) {
  const int tid = threadIdx.x;
  const int L = tid & 63;
  const int wv = tid >> 6;
  const int quad = L >> 4, lo = L & 15;
  const int hi = lo >> 3;  // 0: gates {i,g}, 1: gates {f,o}
  const int cl = lo & 7;   // col within wave's 8-col block

  const int bid = blockIdx.x;
  const int kh = bid >> 5;
  const int d = (bid >> 4) & 1;
  const int wg = bid & 15;
  const int grp = d * 4 + kh;
  const int j0 = wg * 32;
  const int col = j0 + wv * 8 + cl;

  __shared__ unsigned short h_lds[2][8320];  // [buf][16 rows x 520]; rows 8-15 zero

  for (int i = tid; i < 16640; i += 256) ((unsigned short*)h_lds)[i] = 0;

  // Whh B-frags (gate-paired rows). Row for tile ni = (ni*2+hi)*512 + col.
  short8 bfrag[2][16];
#pragma unroll
  for (int ni = 0; ni < 2; ++ni) {
    const unsigned short* wb =
        whh + ((size_t)grp * 2048 + (size_t)((ni * 2 + hi) * 512 + col)) * 512 + quad * 8;
#pragma unroll
    for (int kk = 0; kk < 16; ++kk) bfrag[ni][kk] = *(const short8*)(wb + kk * 32);
  }

  float creg[4] = {0.f, 0.f, 0.f, 0.f};

  // ih gate preacts (bias already folded by GEMM) for s=0
  float ihv[2][4];
  {
    int t0 = d ? 127 : 0;
    const float* base = ih + ((size_t)grp * 1024 + (size_t)t0 * 8) * 2048;
#pragma unroll
    for (int ni = 0; ni < 2; ++ni)
#pragma unroll
      for (int r = 0; r < 4; ++r) {
        int b = quad * 4 + r;
        ihv[ni][r] = (b < 8) ? base[(size_t)b * 2048 + (ni * 2 + hi) * 512 + col] : 0.0f;
      }
  }

  const int srow = tid >> 5;         // batch row 0..7
  const int scol = (tid & 31) * 16;  // h-col base within row (elements)

  for (int s = 0; s < 128; ++s) {
    const int t = d ? (127 - s) : s;
    unsigned short* buf = h_lds[s & 1];

    if (s) {  // stage h_prev into buf[s&1]: poll slot s until non-poison
      const ull* src = stateS + ((size_t)grp * 128 + s) * 1024 + tid * 4;
      ull v0, v1, v2, v3;
      for (;;) {
        v0 = __hip_atomic_load(src + 0, __ATOMIC_RELAXED, __HIP_MEMORY_SCOPE_AGENT);
        v1 = __hip_atomic_load(src + 1, __ATOMIC_RELAXED, __HIP_MEMORY_SCOPE_AGENT);
        v2 = __hip_atomic_load(src + 2, __ATOMIC_RELAXED, __HIP_MEMORY_SCOPE_AGENT);
        v3 = __hip_atomic_load(src + 3, __ATOMIC_RELAXED, __HIP_MEMORY_SCOPE_AGENT);
        if (v0 != POISON && v1 != POISON && v2 != POISON && v3 != POISON) break;
        __builtin_amdgcn_s_sleep(1);
      }
      unsigned short* dl = buf + srow * 520 + scol;
      *(ull*)(dl + 0) = v0;
      *(ull*)(dl + 4) = v1;
      *(ull*)(dl + 8) = v2;
      *(ull*)(dl + 12) = v3;
    }
    __syncthreads();  // staging complete; double-buffer makes this the ONLY barrier

    floatx4 acc[2] = {};
    floatx4 acc2[2] = {};
    {  // A[m][k]: m = lo (batch, rows 8..15 zero); 2 independent chains
      const unsigned short* ar = buf + lo * 520 + quad * 8;
#pragma unroll
      for (int kk = 0; kk < 16; kk += 2) {
        short8 a0 = *(const short8*)(ar + kk * 32);
        short8 a1 = *(const short8*)(ar + (kk + 1) * 32);
#pragma unroll
        for (int ni = 0; ni < 2; ++ni) {
          acc[ni]  = __builtin_amdgcn_mfma_f32_16x16x32_bf16(a0, bfrag[ni][kk], acc[ni], 0, 0, 0);
          acc2[ni] = __builtin_amdgcn_mfma_f32_16x16x32_bf16(a1, bfrag[ni][kk + 1], acc2[ni], 0, 0, 0);
        }
      }
    }

    // prefetch ih for s+1 (plain cached loads; land during pointwise)
    float ihvN[2][4] = {};
    if (s < 127) {
      int tn = d ? (126 - s) : (s + 1);
      const float* base = ih + ((size_t)grp * 1024 + (size_t)tn * 8) * 2048;
#pragma unroll
      for (int ni = 0; ni < 2; ++ni)
#pragma unroll
        for (int r = 0; r < 4; ++r) {
          int b = quad * 4 + r;
          ihvN[ni][r] = (b < 8) ? base[(size_t)b * 2048 + (ni * 2 + hi) * 512 + col] : 0.0f;
        }
    }

    // pointwise + publish + out (no barrier, no gbuf)
#pragma unroll
    for (int r = 0; r < 4; ++r) {
      float v0 = acc[0][r] + acc2[0][r] + ihv[0][r];
      float v1 = acc[1][r] + acc2[1][r] + ihv[1][r];
      float p0 = __shfl_xor(v0, 8);
      float p1 = __shfl_xor(v1, 8);
      float ig = hi ? p0 : v0, fg = hi ? v0 : p0;
      float gg = hi ? p1 : v1, og = hi ? v1 : p1;
      float cn = sigm(fg) * creg[r] + sigm(ig) * tanh_f(gg);
      creg[r] = cn;
      float h = sigm(og) * tanh_f(cn);
      int b = quad * 4 + r;

      unsigned hs = f2bf(h);
      unsigned pk = hs | (__shfl_xor((int)hs, 1) << 16);
      ull w64 = (ull)pk | ((ull)(unsigned)__shfl_xor((int)pk, 2) << 32);
      if (s < 127 && b < 8 && lo < 8 && (lo & 3) == 0) {
        ull* dst = stateS + ((size_t)grp * 128 + (s + 1)) * 1024 + b * 128 + (col >> 2);
        __hip_atomic_store(dst, w64, __ATOMIC_RELAXED, __HIP_MEMORY_SCOPE_AGENT);
      }
      if (b < 8 && lo < 8)
        out[(((size_t)b * 128 + t) * 1024 + d * 512 + col) * 4 + kh] = h;
    }
#pragma unroll
    for (int ni = 0; ni < 2; ++ni)
#pragma unroll
      for (int r = 0; r < 4; ++r) ihv[ni][r] = ihvN[ni][r];
  }
}

extern "C" void kernel_launch(void* const* d_in, const int* in_sizes, int n_in,
                              void* d_out, int out_size, void* d_ws, size_t ws_size,
                              hipStream_t stream) {
  (void)in_sizes; (void)n_in; (void)out_size; (void)ws_size;
  const float* x     = (const float*)d_in[0];
  const float* Wih_f = (const float*)d_in[1];
  const float* Whh_f = (const float*)d_in[2];
  const float* bih_f = (const float*)d_in[3];
  const float* bhh_f = (const float*)d_in[4];
  const float* Wih_b = (const float*)d_in[5];
  const float* Whh_b = (const float*)d_in[6];
  const float* bih_b = (const float*)d_in[7];
  const float* bhh_b = (const float*)d_in[8];
  float* out = (float*)d_out;
  char* ws = (char*)d_ws;

  ull* stateS          = (ull*)ws;                               // 8 MB
  float* ihg           = (float*)(ws + (8ull << 20));            // 64 MB
  unsigned short* Xp   = (unsigned short*)(ws + (72ull << 20));  // 8 MB
  unsigned short* Wihb = (unsigned short*)(ws + (80ull << 20));  // 32 MB
  unsigned short* Whhb = (unsigned short*)(ws + (112ull << 20)); // 16 MB

  prep_k<<<32768, 256, 0, stream>>>(x, Wih_f, Wih_b, Whh_f, Whh_b, Xp, Wihb, Whhb, stateS);
  gemm_ih_k<<<dim3(8, 16, 8), 256, 0, stream>>>(Xp, Wihb, bih_f, bhh_f, bih_b, bhh_b, ihg);
  lstm_rec_k<<<128, 256, 0, stream>>>(ihg, Whhb, out, stateS);
}

// Round 4
// 481.300 us; speedup vs baseline: 1.2156x; 1.1486x over previous
//
#include <hip/hip_runtime.h>
#include <stdint.h>

// Multi_LSTMs: bidirectional 4-head LSTM, BS=8 NT=128 CH=1024 H=512 G=2048.
// R1-R4: poison-poll state exchange, no fences in step loop.
// R5: recurrence MFMA accumulation split into 2 independent chains (487us total).
// R6 FAILED: GEMM/recurrence fusion (blocking ih poll + contention). Reverted.
// R7 FAILED: bundle of 5; bid remap broke same-XCD state exchange (+83us rec).
// R8 (this round): revert recurrence to R5 structure (grp=bid&7 same-XCD
//   exchange, gbuf, 2 barriers, tight poll). Keep prep_k consolidation + bias
//   folded into GEMM. ONE new change: force Whh bfrag register-residency via
//   asm-opaque loads (compiler cannot rematerialize the L2 load; 512-VGPR
//   budget from __launch_bounds__(256,1)). Removes ~32 latency-exposed L2
//   loads/step from the serial chain.

typedef __attribute__((ext_vector_type(8))) short short8;
typedef __attribute__((ext_vector_type(4))) float floatx4;
typedef unsigned long long ull;

#define POISON 0x7FC07FC07FC07FC0ull  // 4 x bf16 NaN (stateS)

#define GLOAD_LDS16(g, l)                                        \
  __builtin_amdgcn_global_load_lds(                              \
      (const __attribute__((address_space(1))) void*)(g),        \
      (__attribute__((address_space(3))) void*)(l), 16, 0, 0)

__device__ __forceinline__ unsigned short f2bf(float f) {
  unsigned u = __float_as_uint(f);
  u = (u + 0x7fffu + ((u >> 16) & 1u)) >> 16;  // RNE
  return (unsigned short)u;
}
__device__ __forceinline__ float sigm(float x) { return 1.0f / (1.0f + __expf(-x)); }
__device__ __forceinline__ float tanh_f(float x) {
  float ax = fabsf(x);
  float e = __expf(-2.0f * ax);
  float t = (1.0f - e) / (1.0f + e);
  return x < 0.0f ? -t : t;
}

// One prep kernel: pack x, cast Wih_f/Wih_b/Whh_f/Whh_b to bf16, poison stateS.
__global__ __launch_bounds__(256) void prep_k(
    const float* __restrict__ x,
    const float* __restrict__ Wih_f, const float* __restrict__ Wih_b,
    const float* __restrict__ Whh_f, const float* __restrict__ Whh_b,
    unsigned short* __restrict__ Xp, unsigned short* __restrict__ Wihb,
    unsigned short* __restrict__ Whhb, ull* __restrict__ stateS) {
  size_t i = (size_t)blockIdx.x * 256 + threadIdx.x;
  if (i < 1048576) {  // pack x: x[8][128][1024][4] f32 -> Xp[4][1024][1024] bf16
    int g = (int)i;
    int m = g >> 10, c = g & 1023;
    int t = m >> 3, b = m & 7;
    float4 v = *(const float4*)(x + ((size_t)((b * 128 + t) * 1024 + c)) * 4);
    Xp[g]           = f2bf(v.x);
    Xp[1048576 + g] = f2bf(v.y);
    Xp[2097152 + g] = f2bf(v.z);
    Xp[3145728 + g] = f2bf(v.w);
  } else if (i < 3145728) {  // Wih_f: 2M float4
    size_t j = i - 1048576;
    float4 v = ((const float4*)Wih_f)[j];
    ushort4 o;
    o.x = f2bf(v.x); o.y = f2bf(v.y); o.z = f2bf(v.z); o.w = f2bf(v.w);
    ((ushort4*)Wihb)[j] = o;
  } else if (i < 5242880) {  // Wih_b
    size_t j = i - 3145728;
    float4 v = ((const float4*)Wih_b)[j];
    ushort4 o;
    o.x = f2bf(v.x); o.y = f2bf(v.y); o.z = f2bf(v.z); o.w = f2bf(v.w);
    ((ushort4*)Wihb)[2097152 + j] = o;
  } else if (i < 6291456) {  // Whh_f: 1M float4
    size_t j = i - 5242880;
    float4 v = ((const float4*)Whh_f)[j];
    ushort4 o;
    o.x = f2bf(v.x); o.y = f2bf(v.y); o.z = f2bf(v.z); o.w = f2bf(v.w);
    ((ushort4*)Whhb)[j] = o;
  } else if (i < 7340032) {  // Whh_b
    size_t j = i - 6291456;
    float4 v = ((const float4*)Whh_b)[j];
    ushort4 o;
    o.x = f2bf(v.x); o.y = f2bf(v.y); o.z = f2bf(v.z); o.w = f2bf(v.w);
    ((ushort4*)Whhb)[1048576 + j] = o;
  } else {  // stateS poison: 1M ull
    stateS[i - 7340032] = POISON;
  }
}

// ih[dk][m][g] = sum_c Xp[kh][m][c] * Wb[dk][g][c] + bih[g] + bhh[g]
// m97 structure: 128x128 tile, BK=32, global_load_lds(16B), 4 waves 2x2.
__global__ __launch_bounds__(256) void gemm_ih_k(
    const unsigned short* __restrict__ Xp, const unsigned short* __restrict__ Wb,
    const float* __restrict__ bihf, const float* __restrict__ bhhf,
    const float* __restrict__ bihb, const float* __restrict__ bhhb,
    float* __restrict__ ih) {
  const int mt = blockIdx.x, ntl = blockIdx.y, dk = blockIdx.z;
  const int kh = dk & 3;
  const int tid = threadIdx.x;
  const int L = tid & 63, w = tid >> 6;
  const int wm = w & 1, wn = w >> 1;
  const int quad = L >> 4, lo = L & 15;

  __shared__ unsigned short As[128 * 32];  // 8 KB, no pad (glds contiguity)
  __shared__ unsigned short Bs[128 * 32];

  const unsigned short* Ab = Xp + (size_t)kh * 1048576 + (size_t)mt * 128 * 1024;
  const unsigned short* Bb = Wb + (size_t)dk * 2097152 + (size_t)ntl * 128 * 1024;

  floatx4 acc[4][4] = {};

  for (int kc = 0; kc < 32; ++kc) {
#pragma unroll
    for (int q = 0; q < 2; ++q) {
      int c = q * 256 + w * 64 + L;       // 16B chunk id, 0..511
      int ldsb = (q * 256 + w * 64) * 8;  // wave-uniform base (shorts)
      GLOAD_LDS16(Ab + (size_t)(c >> 2) * 1024 + kc * 32 + (c & 3) * 8, As + ldsb);
      GLOAD_LDS16(Bb + (size_t)(c >> 2) * 1024 + kc * 32 + (c & 3) * 8, Bs + ldsb);
    }
    __syncthreads();  // implicit vmcnt(0): LDS tiles ready
    short8 af[4], bf[4];
#pragma unroll
    for (int mi = 0; mi < 4; ++mi)
      af[mi] = *(const short8*)(As + (wm * 64 + mi * 16 + lo) * 32 + quad * 8);
#pragma unroll
    for (int ni = 0; ni < 4; ++ni)
      bf[ni] = *(const short8*)(Bs + (wn * 64 + ni * 16 + lo) * 32 + quad * 8);
#pragma unroll
    for (int mi = 0; mi < 4; ++mi)
#pragma unroll
      for (int ni = 0; ni < 4; ++ni)
        acc[mi][ni] = __builtin_amdgcn_mfma_f32_16x16x32_bf16(af[mi], bf[ni], acc[mi][ni], 0, 0, 0);
    __syncthreads();  // LDS reads done before next stage
  }

  const float* bihp = (dk < 4) ? bihf : bihb;
  const float* bhhp = (dk < 4) ? bhhf : bhhb;
#pragma unroll
  for (int ni = 0; ni < 4; ++ni) {
    int g = ntl * 128 + wn * 64 + ni * 16 + lo;
    float bv = bihp[kh * 2048 + g] + bhhp[kh * 2048 + g];
#pragma unroll
    for (int mi = 0; mi < 4; ++mi)
#pragma unroll
      for (int r = 0; r < 4; ++r) {
        int m = mt * 128 + wm * 64 + mi * 16 + quad * 4 + r;
        ih[((size_t)dk * 1024 + m) * 2048 + g] = acc[mi][ni][r] + bv;
      }
  }
}

// Persistent recurrence (R5 structure). grid=128: grp = bid&7 (same-XCD
// consumer set), wg = bid>>3 owns h-cols [wg*32, +32). Wave w = gate, 2 N-tiles.
// stateS[grp][s][8][128] ull: slot s = h input for step s; poison-polled.
__global__ __launch_bounds__(256, 1) void lstm_rec_k(
    const float* __restrict__ ih, const unsigned short* __restrict__ whh,
    float* __restrict__ out, ull* __restrict__ stateS) {
  const int tid = threadIdx.x;
  const int L = tid & 63;
  const int w = tid >> 6;
  const int grp = blockIdx.x & 7;
  const int d = grp >> 2, kh = grp & 3;
  const int wg = blockIdx.x >> 3;
  const int j0 = wg * 32;
  const int quad = L >> 4, lo = L & 15;

  __shared__ unsigned short h_lds[16 * 520];  // rows 8..15 stay zero (M-pad)
  __shared__ float gbuf[4][8][32];            // [gate][b][jj]

  for (int i = tid; i < 16 * 520; i += 256) h_lds[i] = 0;

  // Whh slice -> register B-frags, asm-pinned: the empty asm's output is
  // opaque, so the allocator CANNOT rematerialize by re-loading from whh
  // (round-1/3 showed it otherwise reloads every step: VGPR_Count 100/112).
  short8 bfrag[2][16];
#pragma unroll
  for (int ni = 0; ni < 2; ++ni) {
    const unsigned short* wb =
        whh + ((size_t)grp * 2048 + (size_t)(w * 512 + j0 + ni * 16 + lo)) * 512 + quad * 8;
#pragma unroll
    for (int kk = 0; kk < 16; ++kk) {
      short8 t = *(const short8*)(wb + kk * 32);
      asm volatile("" : "+v"(t));
      bfrag[ni][kk] = t;
    }
  }

  const int pb = tid >> 5, pjj = tid & 31;  // pointwise cell (b, jj)
  float creg = 0.0f;

  // prefetch ih gates for s=0 (bias already folded by GEMM)
  float ihv[2][4];
  {
    int t0 = d ? 127 : 0;
#pragma unroll
    for (int ni = 0; ni < 2; ++ni) {
      const float* ihp =
          ih + ((size_t)grp * 1024 + (size_t)t0 * 8) * 2048 + (w * 512 + j0 + ni * 16 + lo);
#pragma unroll
      for (int r = 0; r < 4; ++r) {
        int b = quad * 4 + r;
        ihv[ni][r] = (b < 8) ? ihp[(size_t)b * 2048] : 0.0f;
      }
    }
  }

  const int srow = tid >> 5;         // batch row 0..7
  const int scol = (tid & 31) * 16;  // h-col base within row (elements)

  for (int s = 0; s < 128; ++s) {
    const int t = d ? (127 - s) : s;

    if (s) {  // stage h_prev: poll slot s until this thread's producers wrote it
      const ull* src = stateS + ((size_t)grp * 128 + s) * 1024 + tid * 4;
      ull v0, v1, v2, v3;
      do {
        v0 = __hip_atomic_load(src + 0, __ATOMIC_RELAXED, __HIP_MEMORY_SCOPE_AGENT);
        v1 = __hip_atomic_load(src + 1, __ATOMIC_RELAXED, __HIP_MEMORY_SCOPE_AGENT);
        v2 = __hip_atomic_load(src + 2, __ATOMIC_RELAXED, __HIP_MEMORY_SCOPE_AGENT);
        v3 = __hip_atomic_load(src + 3, __ATOMIC_RELAXED, __HIP_MEMORY_SCOPE_AGENT);
      } while (v0 == POISON || v1 == POISON || v2 == POISON || v3 == POISON);
      unsigned short* dl = h_lds + srow * 520 + scol;
      *(ull*)(dl + 0) = v0;
      *(ull*)(dl + 4) = v1;
      *(ull*)(dl + 8) = v2;
      *(ull*)(dl + 12) = v3;
    }
    __syncthreads();

    floatx4 acc[2] = {};
    floatx4 acc2[2] = {};
    {  // A[m][k]: m = L&15 (batch, rows 8..15 zero); 2 independent chains
      const unsigned short* ar = h_lds + lo * 520 + quad * 8;
#pragma unroll
      for (int kk = 0; kk < 16; kk += 2) {
        short8 a0 = *(const short8*)(ar + kk * 32);
        short8 a1 = *(const short8*)(ar + (kk + 1) * 32);
#pragma unroll
        for (int ni = 0; ni < 2; ++ni) {
          acc[ni]  = __builtin_amdgcn_mfma_f32_16x16x32_bf16(a0, bfrag[ni][kk], acc[ni], 0, 0, 0);
          acc2[ni] = __builtin_amdgcn_mfma_f32_16x16x32_bf16(a1, bfrag[ni][kk + 1], acc2[ni], 0, 0, 0);
        }
      }
    }
#pragma unroll
    for (int ni = 0; ni < 2; ++ni)
#pragma unroll
      for (int r = 0; r < 4; ++r) {
        int b = quad * 4 + r;
        if (b < 8) gbuf[w][b][ni * 16 + lo] = acc[ni][r] + acc2[ni][r] + ihv[ni][r];
      }

    if (s < 127) {  // prefetch ih for s+1 (flies during pointwise + next poll)
      int tn = d ? (126 - s) : (s + 1);
#pragma unroll
      for (int ni = 0; ni < 2; ++ni) {
        const float* ihp =
            ih + ((size_t)grp * 1024 + (size_t)tn * 8) * 2048 + (w * 512 + j0 + ni * 16 + lo);
#pragma unroll
        for (int r = 0; r < 4; ++r) {
          int b = quad * 4 + r;
          ihv[ni][r] = (b < 8) ? ihp[(size_t)b * 2048] : 0.0f;
        }
      }
    }
    __syncthreads();

    // pointwise LSTM cell: one (b, jj) per thread
    {
      float ig = gbuf[0][pb][pjj], fg = gbuf[1][pb][pjj];
      float gg = gbuf[2][pb][pjj], og = gbuf[3][pb][pjj];
      float cn = sigm(fg) * creg + sigm(ig) * tanh_f(gg);
      creg = cn;
      float h = sigm(og) * tanh_f(cn);

      if (s < 127) {  // publish h into slot s+1: shfl-pack 4 lanes -> 8B store
        unsigned hs = f2bf(h);
        int base = L & ~3;
        unsigned v0 = __shfl(hs, base + 0);
        unsigned v1 = __shfl(hs, base + 1);
        unsigned v2 = __shfl(hs, base + 2);
        unsigned v3 = __shfl(hs, base + 3);
        if ((L & 3) == 0) {
          ull wv = (ull)v0 | ((ull)v1 << 16) | ((ull)v2 << 32) | ((ull)v3 << 48);
          ull* dst = stateS + ((size_t)grp * 128 + (s + 1)) * 1024 + pb * 128 + ((j0 + pjj) >> 2);
          __hip_atomic_store(dst, wv, __ATOMIC_RELAXED, __HIP_MEMORY_SCOPE_AGENT);
        }
      }
      out[(((size_t)pb * 128 + t) * 1024 + d * 512 + j0 + pjj) * 4 + kh] = h;
    }
  }
}

extern "C" void kernel_launch(void* const* d_in, const int* in_sizes, int n_in,
                              void* d_out, int out_size, void* d_ws, size_t ws_size,
                              hipStream_t stream) {
  (void)in_sizes; (void)n_in; (void)out_size; (void)ws_size;
  const float* x     = (const float*)d_in[0];
  const float* Wih_f = (const float*)d_in[1];
  const float* Whh_f = (const float*)d_in[2];
  const float* bih_f = (const float*)d_in[3];
  const float* bhh_f = (const float*)d_in[4];
  const float* Wih_b = (const float*)d_in[5];
  const float* Whh_b = (const float*)d_in[6];
  const float* bih_b = (const float*)d_in[7];
  const float* bhh_b = (const float*)d_in[8];
  float* out = (float*)d_out;
  char* ws = (char*)d_ws;

  ull* stateS          = (ull*)ws;                               // 8 MB
  float* ihg           = (float*)(ws + (8ull << 20));            // 64 MB
  unsigned short* Xp   = (unsigned short*)(ws + (72ull << 20));  // 8 MB
  unsigned short* Wihb = (unsigned short*)(ws + (80ull << 20));  // 32 MB
  unsigned short* Whhb = (unsigned short*)(ws + (112ull << 20)); // 16 MB

  prep_k<<<32768, 256, 0, stream>>>(x, Wih_f, Wih_b, Whh_f, Whh_b, Xp, Wihb, Whhb, stateS);
  gemm_ih_k<<<dim3(8, 16, 8), 256, 0, stream>>>(Xp, Wihb, bih_f, bhh_f, bih_b, bhh_b, ihg);
  lstm_rec_k<<<128, 256, 0, stream>>>(ihg, Whhb, out, stateS);
}

// Round 5
// 479.704 us; speedup vs baseline: 1.2196x; 1.0033x over previous
//
#include <hip/hip_runtime.h>
#include <stdint.h>

// Multi_LSTMs: bidirectional 4-head LSTM, BS=8 NT=128 CH=1024 H=512 G=2048.
// R1-R4: poison-poll state exchange, no fences in step loop.
// R5: recurrence MFMA accumulation split into 2 independent chains (487us total).
// R6 FAILED: GEMM/recurrence fusion (blocking ih poll + contention). Reverted.
// R7 FAILED: bundle of 5 (remap/gate-pairing/1-barrier). Reverted.
// R8: asm-pin of bfrag: NO VGPR change, +10us -> residency theory dead; bfrag
//   already resident. Prologue consolidation kept (prep_k + bias-in-GEMM).
// R9 (this round):
//   a) rec: drop asm pin (back to R1/R5 form). Poll = spin on word0 ONLY
//      (8B/thread/iter, 4x less spin traffic at the LLC coherence point),
//      then read+verify words 1..3 (same producer wave-store line; common
//      case single pass). Theory: agent-scope polls resolve at LLC (XCD L2s
//      non-coherent); 4 TB/s of spin reads was inflating exchange RT ~4x.
//   b) gemm: XCD-panel swizzle -- all 8 mt-tiles of a (dk,ntl) B-panel on one
//      XCD (bid&7 = panel&7) -> B-panel reuse becomes L2-local.

typedef __attribute__((ext_vector_type(8))) short short8;
typedef __attribute__((ext_vector_type(4))) float floatx4;
typedef unsigned long long ull;

#define POISON 0x7FC07FC07FC07FC0ull  // 4 x bf16 NaN (stateS)

#define GLOAD_LDS16(g, l)                                        \
  __builtin_amdgcn_global_load_lds(                              \
      (const __attribute__((address_space(1))) void*)(g),        \
      (__attribute__((address_space(3))) void*)(l), 16, 0, 0)

__device__ __forceinline__ unsigned short f2bf(float f) {
  unsigned u = __float_as_uint(f);
  u = (u + 0x7fffu + ((u >> 16) & 1u)) >> 16;  // RNE
  return (unsigned short)u;
}
__device__ __forceinline__ float sigm(float x) { return 1.0f / (1.0f + __expf(-x)); }
__device__ __forceinline__ float tanh_f(float x) {
  float ax = fabsf(x);
  float e = __expf(-2.0f * ax);
  float t = (1.0f - e) / (1.0f + e);
  return x < 0.0f ? -t : t;
}

// One prep kernel: pack x, cast Wih_f/Wih_b/Whh_f/Whh_b to bf16, poison stateS.
__global__ __launch_bounds__(256) void prep_k(
    const float* __restrict__ x,
    const float* __restrict__ Wih_f, const float* __restrict__ Wih_b,
    const float* __restrict__ Whh_f, const float* __restrict__ Whh_b,
    unsigned short* __restrict__ Xp, unsigned short* __restrict__ Wihb,
    unsigned short* __restrict__ Whhb, ull* __restrict__ stateS) {
  size_t i = (size_t)blockIdx.x * 256 + threadIdx.x;
  if (i < 1048576) {  // pack x: x[8][128][1024][4] f32 -> Xp[4][1024][1024] bf16
    int g = (int)i;
    int m = g >> 10, c = g & 1023;
    int t = m >> 3, b = m & 7;
    float4 v = *(const float4*)(x + ((size_t)((b * 128 + t) * 1024 + c)) * 4);
    Xp[g]           = f2bf(v.x);
    Xp[1048576 + g] = f2bf(v.y);
    Xp[2097152 + g] = f2bf(v.z);
    Xp[3145728 + g] = f2bf(v.w);
  } else if (i < 3145728) {  // Wih_f: 2M float4
    size_t j = i - 1048576;
    float4 v = ((const float4*)Wih_f)[j];
    ushort4 o;
    o.x = f2bf(v.x); o.y = f2bf(v.y); o.z = f2bf(v.z); o.w = f2bf(v.w);
    ((ushort4*)Wihb)[j] = o;
  } else if (i < 5242880) {  // Wih_b
    size_t j = i - 3145728;
    float4 v = ((const float4*)Wih_b)[j];
    ushort4 o;
    o.x = f2bf(v.x); o.y = f2bf(v.y); o.z = f2bf(v.z); o.w = f2bf(v.w);
    ((ushort4*)Wihb)[2097152 + j] = o;
  } else if (i < 6291456) {  // Whh_f: 1M float4
    size_t j = i - 5242880;
    float4 v = ((const float4*)Whh_f)[j];
    ushort4 o;
    o.x = f2bf(v.x); o.y = f2bf(v.y); o.z = f2bf(v.z); o.w = f2bf(v.w);
    ((ushort4*)Whhb)[j] = o;
  } else if (i < 7340032) {  // Whh_b
    size_t j = i - 6291456;
    float4 v = ((const float4*)Whh_b)[j];
    ushort4 o;
    o.x = f2bf(v.x); o.y = f2bf(v.y); o.z = f2bf(v.z); o.w = f2bf(v.w);
    ((ushort4*)Whhb)[1048576 + j] = o;
  } else {  // stateS poison: 1M ull
    stateS[i - 7340032] = POISON;
  }
}

// ih[dk][m][g] = sum_c Xp[kh][m][c] * Wb[dk][g][c] + bih[g] + bhh[g]
// m97 structure: 128x128 tile, BK=32, global_load_lds(16B), 4 waves 2x2.
// 1-D grid, XCD-panel swizzle: panel p=(dk,ntl) pinned to XCD p&7; its 8
// mt-tiles are blocks bid = (p&7) + 8*((p>>3)*8 + mt)  (bijective over 1024).
__global__ __launch_bounds__(256) void gemm_ih_k(
    const unsigned short* __restrict__ Xp, const unsigned short* __restrict__ Wb,
    const float* __restrict__ bihf, const float* __restrict__ bhhf,
    const float* __restrict__ bihb, const float* __restrict__ bhhb,
    float* __restrict__ ih) {
  const int bid = blockIdx.x;
  const int xcd = bid & 7;
  const int q   = bid >> 3;    // 0..127
  const int mt  = q & 7;
  const int p   = (q >> 3) * 8 + xcd;  // panel 0..127
  const int dk  = p >> 4;
  const int ntl = p & 15;
  const int kh = dk & 3;
  const int tid = threadIdx.x;
  const int L = tid & 63, w = tid >> 6;
  const int wm = w & 1, wn = w >> 1;
  const int quad = L >> 4, lo = L & 15;

  __shared__ unsigned short As[128 * 32];  // 8 KB, no pad (glds contiguity)
  __shared__ unsigned short Bs[128 * 32];

  const unsigned short* Ab = Xp + (size_t)kh * 1048576 + (size_t)mt * 128 * 1024;
  const unsigned short* Bb = Wb + (size_t)dk * 2097152 + (size_t)ntl * 128 * 1024;

  floatx4 acc[4][4] = {};

  for (int kc = 0; kc < 32; ++kc) {
#pragma unroll
    for (int ph = 0; ph < 2; ++ph) {
      int c = ph * 256 + w * 64 + L;       // 16B chunk id, 0..511
      int ldsb = (ph * 256 + w * 64) * 8;  // wave-uniform base (shorts)
      GLOAD_LDS16(Ab + (size_t)(c >> 2) * 1024 + kc * 32 + (c & 3) * 8, As + ldsb);
      GLOAD_LDS16(Bb + (size_t)(c >> 2) * 1024 + kc * 32 + (c & 3) * 8, Bs + ldsb);
    }
    __syncthreads();  // implicit vmcnt(0): LDS tiles ready
    short8 af[4], bf[4];
#pragma unroll
    for (int mi = 0; mi < 4; ++mi)
      af[mi] = *(const short8*)(As + (wm * 64 + mi * 16 + lo) * 32 + quad * 8);
#pragma unroll
    for (int ni = 0; ni < 4; ++ni)
      bf[ni] = *(const short8*)(Bs + (wn * 64 + ni * 16 + lo) * 32 + quad * 8);
#pragma unroll
    for (int mi = 0; mi < 4; ++mi)
#pragma unroll
      for (int ni = 0; ni < 4; ++ni)
        acc[mi][ni] = __builtin_amdgcn_mfma_f32_16x16x32_bf16(af[mi], bf[ni], acc[mi][ni], 0, 0, 0);
    __syncthreads();  // LDS reads done before next stage
  }

  const float* bihp = (dk < 4) ? bihf : bihb;
  const float* bhhp = (dk < 4) ? bhhf : bhhb;
#pragma unroll
  for (int ni = 0; ni < 4; ++ni) {
    int g = ntl * 128 + wn * 64 + ni * 16 + lo;
    float bv = bihp[kh * 2048 + g] + bhhp[kh * 2048 + g];
#pragma unroll
    for (int mi = 0; mi < 4; ++mi)
#pragma unroll
      for (int r = 0; r < 4; ++r) {
        int m = mt * 128 + wm * 64 + mi * 16 + quad * 4 + r;
        ih[((size_t)dk * 1024 + m) * 2048 + g] = acc[mi][ni][r] + bv;
      }
  }
}

// Persistent recurrence (R5 structure). grid=128: grp = bid&7, wg = bid>>3
// owns h-cols [wg*32, +32). Wave w = gate, 2 N-tiles each.
// stateS[grp][s][8][128] ull: slot s = h input for step s; poison-polled.
// R9: spin on word0 only (4x less spin traffic at the LLC), then read+verify
// words 1..3 (same producer wave-store; common case one pass).
__global__ __launch_bounds__(256) void lstm_rec_k(
    const float* __restrict__ ih, const unsigned short* __restrict__ whh,
    float* __restrict__ out, ull* __restrict__ stateS) {
  const int tid = threadIdx.x;
  const int L = tid & 63;
  const int w = tid >> 6;
  const int grp = blockIdx.x & 7;
  const int d = grp >> 2, kh = grp & 3;
  const int wg = blockIdx.x >> 3;
  const int j0 = wg * 32;
  const int quad = L >> 4, lo = L & 15;

  __shared__ unsigned short h_lds[16 * 520];  // rows 8..15 stay zero (M-pad)
  __shared__ float gbuf[4][8][32];            // [gate][b][jj]

  for (int i = tid; i < 16 * 520; i += 256) h_lds[i] = 0;

  // Whh slice -> B-frags (compiler keeps these resident; R8 proved no reloads)
  short8 bfrag[2][16];
#pragma unroll
  for (int ni = 0; ni < 2; ++ni) {
    const unsigned short* wb =
        whh + ((size_t)grp * 2048 + (size_t)(w * 512 + j0 + ni * 16 + lo)) * 512 + quad * 8;
#pragma unroll
    for (int kk = 0; kk < 16; ++kk) bfrag[ni][kk] = *(const short8*)(wb + kk * 32);
  }

  const int pb = tid >> 5, pjj = tid & 31;  // pointwise cell (b, jj)
  float creg = 0.0f;

  // prefetch ih gates for s=0 (bias already folded by GEMM)
  float ihv[2][4];
  {
    int t0 = d ? 127 : 0;
#pragma unroll
    for (int ni = 0; ni < 2; ++ni) {
      const float* ihp =
          ih + ((size_t)grp * 1024 + (size_t)t0 * 8) * 2048 + (w * 512 + j0 + ni * 16 + lo);
#pragma unroll
      for (int r = 0; r < 4; ++r) {
        int b = quad * 4 + r;
        ihv[ni][r] = (b < 8) ? ihp[(size_t)b * 2048] : 0.0f;
      }
    }
  }

  const int srow = tid >> 5;         // batch row 0..7
  const int scol = (tid & 31) * 16;  // h-col base within row (elements)

  for (int s = 0; s < 128; ++s) {
    const int t = d ? (127 - s) : s;

    if (s) {  // stage h_prev: spin on word0, then read+verify words 1..3
      const ull* src = stateS + ((size_t)grp * 128 + s) * 1024 + tid * 4;
      ull v0, v1, v2, v3;
      do {
        v0 = __hip_atomic_load(src + 0, __ATOMIC_RELAXED, __HIP_MEMORY_SCOPE_AGENT);
      } while (v0 == POISON);
      do {
        v1 = __hip_atomic_load(src + 1, __ATOMIC_RELAXED, __HIP_MEMORY_SCOPE_AGENT);
        v2 = __hip_atomic_load(src + 2, __ATOMIC_RELAXED, __HIP_MEMORY_SCOPE_AGENT);
        v3 = __hip_atomic_load(src + 3, __ATOMIC_RELAXED, __HIP_MEMORY_SCOPE_AGENT);
      } while (v1 == POISON || v2 == POISON || v3 == POISON);
      unsigned short* dl = h_lds + srow * 520 + scol;
      *(ull*)(dl + 0) = v0;
      *(ull*)(dl + 4) = v1;
      *(ull*)(dl + 8) = v2;
      *(ull*)(dl + 12) = v3;
    }
    __syncthreads();

    floatx4 acc[2] = {};
    floatx4 acc2[2] = {};
    {  // A[m][k]: m = L&15 (batch, rows 8..15 zero); 2 independent chains
      const unsigned short* ar = h_lds + lo * 520 + quad * 8;
#pragma unroll
      for (int kk = 0; kk < 16; kk += 2) {
        short8 a0 = *(const short8*)(ar + kk * 32);
        short8 a1 = *(const short8*)(ar + (kk + 1) * 32);
#pragma unroll
        for (int ni = 0; ni < 2; ++ni) {
          acc[ni]  = __builtin_amdgcn_mfma_f32_16x16x32_bf16(a0, bfrag[ni][kk], acc[ni], 0, 0, 0);
          acc2[ni] = __builtin_amdgcn_mfma_f32_16x16x32_bf16(a1, bfrag[ni][kk + 1], acc2[ni], 0, 0, 0);
        }
      }
    }
#pragma unroll
    for (int ni = 0; ni < 2; ++ni)
#pragma unroll
      for (int r = 0; r < 4; ++r) {
        int b = quad * 4 + r;
        if (b < 8) gbuf[w][b][ni * 16 + lo] = acc[ni][r] + acc2[ni][r] + ihv[ni][r];
      }

    if (s < 127) {  // prefetch ih for s+1 (flies during pointwise + next poll)
      int tn = d ? (126 - s) : (s + 1);
#pragma unroll
      for (int ni = 0; ni < 2; ++ni) {
        const float* ihp =
            ih + ((size_t)grp * 1024 + (size_t)tn * 8) * 2048 + (w * 512 + j0 + ni * 16 + lo);
#pragma unroll
        for (int r = 0; r < 4; ++r) {
          int b = quad * 4 + r;
          ihv[ni][r] = (b < 8) ? ihp[(size_t)b * 2048] : 0.0f;
        }
      }
    }
    __syncthreads();

    // pointwise LSTM cell: one (b, jj) per thread
    {
      float ig = gbuf[0][pb][pjj], fg = gbuf[1][pb][pjj];
      float gg = gbuf[2][pb][pjj], og = gbuf[3][pb][pjj];
      float cn = sigm(fg) * creg + sigm(ig) * tanh_f(gg);
      creg = cn;
      float h = sigm(og) * tanh_f(cn);

      if (s < 127) {  // publish h into slot s+1: shfl-pack 4 lanes -> 8B store
        unsigned hs = f2bf(h);
        int base = L & ~3;
        unsigned v0 = __shfl(hs, base + 0);
        unsigned v1 = __shfl(hs, base + 1);
        unsigned v2 = __shfl(hs, base + 2);
        unsigned v3 = __shfl(hs, base + 3);
        if ((L & 3) == 0) {
          ull wv = (ull)v0 | ((ull)v1 << 16) | ((ull)v2 << 32) | ((ull)v3 << 48);
          ull* dst = stateS + ((size_t)grp * 128 + (s + 1)) * 1024 + pb * 128 + ((j0 + pjj) >> 2);
          __hip_atomic_store(dst, wv, __ATOMIC_RELAXED, __HIP_MEMORY_SCOPE_AGENT);
        }
      }
      out[(((size_t)pb * 128 + t) * 1024 + d * 512 + j0 + pjj) * 4 + kh] = h;
    }
  }
}

extern "C" void kernel_launch(void* const* d_in, const int* in_sizes, int n_in,
                              void* d_out, int out_size, void* d_ws, size_t ws_size,
                              hipStream_t stream) {
  (void)in_sizes; (void)n_in; (void)out_size; (void)ws_size;
  const float* x     = (const float*)d_in[0];
  const float* Wih_f = (const float*)d_in[1];
  const float* Whh_f = (const float*)d_in[2];
  const float* bih_f = (const float*)d_in[3];
  const float* bhh_f = (const float*)d_in[4];
  const float* Wih_b = (const float*)d_in[5];
  const float* Whh_b = (const float*)d_in[6];
  const float* bih_b = (const float*)d_in[7];
  const float* bhh_b = (const float*)d_in[8];
  float* out = (float*)d_out;
  char* ws = (char*)d_ws;

  ull* stateS          = (ull*)ws;                               // 8 MB
  float* ihg           = (float*)(ws + (8ull << 20));            // 64 MB
  unsigned short* Xp   = (unsigned short*)(ws + (72ull << 20));  // 8 MB
  unsigned short* Wihb = (unsigned short*)(ws + (80ull << 20));  // 32 MB
  unsigned short* Whhb = (unsigned short*)(ws + (112ull << 20)); // 16 MB

  prep_k<<<32768, 256, 0, stream>>>(x, Wih_f, Wih_b, Whh_f, Whh_b, Xp, Wihb, Whhb, stateS);
  gemm_ih_k<<<1024, 256, 0, stream>>>(Xp, Wihb, bih_f, bhh_f, bih_b, bhh_b, ihg);
  lstm_rec_k<<<128, 256, 0, stream>>>(ihg, Whhb, out, stateS);
}

// Round 6
// 460.360 us; speedup vs baseline: 1.2709x; 1.0420x over previous
//
#include <hip/hip_runtime.h>
#include <stdint.h>

// Multi_LSTMs: bidirectional 4-head LSTM, BS=8 NT=128 CH=1024 H=512 G=2048.
// R1-R4: poison-poll state exchange, no fences in step loop.
// R5: recurrence MFMA accumulation split into 2 independent chains.
// R6 FAILED: GEMM/recurrence fusion. R7 FAILED: 5-change bundle.
// R8 REFUTED residency theory (asm pin: no VGPR change, +10us).
// R9 REFUTED spin-traffic theory (word0-only spin: +4us). Panel swizzle ~neutral.
// R10 (this round): __syncthreads emits s_waitcnt vmcnt(0) before s_barrier,
//   which drains the ~900cy HBM ih-prefetch (barrier #2) and the out/publish
//   store acks (barrier #1) ON the serial chain every step (~0.6us/step).
//   Replace both with raw s_barrier + lgkmcnt(0)-only drain:
//     - LDS visibility (h_lds stage, gbuf) needs only lgkmcnt(0).
//     - publish/out stores are fire-and-forget (poison-poll protocol).
//     - ih prefetch consumers get compiler-auto waitcnt at use.
//   Poll reverted to the proven 4-word form (R1/R5 baseline).

typedef __attribute__((ext_vector_type(8))) short short8;
typedef __attribute__((ext_vector_type(4))) float floatx4;
typedef unsigned long long ull;

#define POISON 0x7FC07FC07FC07FC0ull  // 4 x bf16 NaN (stateS)

// Barrier WITHOUT the implicit vmcnt(0) drain: only LDS ops must be visible.
#define LDS_BARRIER()                                       \
  do {                                                      \
    asm volatile("s_waitcnt lgkmcnt(0)" ::: "memory");      \
    __builtin_amdgcn_s_barrier();                           \
  } while (0)

#define GLOAD_LDS16(g, l)                                        \
  __builtin_amdgcn_global_load_lds(                              \
      (const __attribute__((address_space(1))) void*)(g),        \
      (__attribute__((address_space(3))) void*)(l), 16, 0, 0)

__device__ __forceinline__ unsigned short f2bf(float f) {
  unsigned u = __float_as_uint(f);
  u = (u + 0x7fffu + ((u >> 16) & 1u)) >> 16;  // RNE
  return (unsigned short)u;
}
__device__ __forceinline__ float sigm(float x) { return 1.0f / (1.0f + __expf(-x)); }
__device__ __forceinline__ float tanh_f(float x) {
  float ax = fabsf(x);
  float e = __expf(-2.0f * ax);
  float t = (1.0f - e) / (1.0f + e);
  return x < 0.0f ? -t : t;
}

// One prep kernel: pack x, cast Wih_f/Wih_b/Whh_f/Whh_b to bf16, poison stateS.
__global__ __launch_bounds__(256) void prep_k(
    const float* __restrict__ x,
    const float* __restrict__ Wih_f, const float* __restrict__ Wih_b,
    const float* __restrict__ Whh_f, const float* __restrict__ Whh_b,
    unsigned short* __restrict__ Xp, unsigned short* __restrict__ Wihb,
    unsigned short* __restrict__ Whhb, ull* __restrict__ stateS) {
  size_t i = (size_t)blockIdx.x * 256 + threadIdx.x;
  if (i < 1048576) {  // pack x: x[8][128][1024][4] f32 -> Xp[4][1024][1024] bf16
    int g = (int)i;
    int m = g >> 10, c = g & 1023;
    int t = m >> 3, b = m & 7;
    float4 v = *(const float4*)(x + ((size_t)((b * 128 + t) * 1024 + c)) * 4);
    Xp[g]           = f2bf(v.x);
    Xp[1048576 + g] = f2bf(v.y);
    Xp[2097152 + g] = f2bf(v.z);
    Xp[3145728 + g] = f2bf(v.w);
  } else if (i < 3145728) {  // Wih_f: 2M float4
    size_t j = i - 1048576;
    float4 v = ((const float4*)Wih_f)[j];
    ushort4 o;
    o.x = f2bf(v.x); o.y = f2bf(v.y); o.z = f2bf(v.z); o.w = f2bf(v.w);
    ((ushort4*)Wihb)[j] = o;
  } else if (i < 5242880) {  // Wih_b
    size_t j = i - 3145728;
    float4 v = ((const float4*)Wih_b)[j];
    ushort4 o;
    o.x = f2bf(v.x); o.y = f2bf(v.y); o.z = f2bf(v.z); o.w = f2bf(v.w);
    ((ushort4*)Wihb)[2097152 + j] = o;
  } else if (i < 6291456) {  // Whh_f: 1M float4
    size_t j = i - 5242880;
    float4 v = ((const float4*)Whh_f)[j];
    ushort4 o;
    o.x = f2bf(v.x); o.y = f2bf(v.y); o.z = f2bf(v.z); o.w = f2bf(v.w);
    ((ushort4*)Whhb)[j] = o;
  } else if (i < 7340032) {  // Whh_b
    size_t j = i - 6291456;
    float4 v = ((const float4*)Whh_b)[j];
    ushort4 o;
    o.x = f2bf(v.x); o.y = f2bf(v.y); o.z = f2bf(v.z); o.w = f2bf(v.w);
    ((ushort4*)Whhb)[1048576 + j] = o;
  } else {  // stateS poison: 1M ull
    stateS[i - 7340032] = POISON;
  }
}

// ih[dk][m][g] = sum_c Xp[kh][m][c] * Wb[dk][g][c] + bih[g] + bhh[g]
// m97 structure: 128x128 tile, BK=32, global_load_lds(16B), 4 waves 2x2.
// XCD-panel swizzle (R9, neutral but kept): panel p=(dk,ntl) pinned to XCD p&7.
__global__ __launch_bounds__(256) void gemm_ih_k(
    const unsigned short* __restrict__ Xp, const unsigned short* __restrict__ Wb,
    const float* __restrict__ bihf, const float* __restrict__ bhhf,
    const float* __restrict__ bihb, const float* __restrict__ bhhb,
    float* __restrict__ ih) {
  const int bid = blockIdx.x;
  const int xcd = bid & 7;
  const int q   = bid >> 3;    // 0..127
  const int mt  = q & 7;
  const int p   = (q >> 3) * 8 + xcd;  // panel 0..127
  const int dk  = p >> 4;
  const int ntl = p & 15;
  const int kh = dk & 3;
  const int tid = threadIdx.x;
  const int L = tid & 63, w = tid >> 6;
  const int wm = w & 1, wn = w >> 1;
  const int quad = L >> 4, lo = L & 15;

  __shared__ unsigned short As[128 * 32];  // 8 KB, no pad (glds contiguity)
  __shared__ unsigned short Bs[128 * 32];

  const unsigned short* Ab = Xp + (size_t)kh * 1048576 + (size_t)mt * 128 * 1024;
  const unsigned short* Bb = Wb + (size_t)dk * 2097152 + (size_t)ntl * 128 * 1024;

  floatx4 acc[4][4] = {};

  for (int kc = 0; kc < 32; ++kc) {
#pragma unroll
    for (int ph = 0; ph < 2; ++ph) {
      int c = ph * 256 + w * 64 + L;       // 16B chunk id, 0..511
      int ldsb = (ph * 256 + w * 64) * 8;  // wave-uniform base (shorts)
      GLOAD_LDS16(Ab + (size_t)(c >> 2) * 1024 + kc * 32 + (c & 3) * 8, As + ldsb);
      GLOAD_LDS16(Bb + (size_t)(c >> 2) * 1024 + kc * 32 + (c & 3) * 8, Bs + ldsb);
    }
    __syncthreads();  // implicit vmcnt(0): LDS tiles ready (needed here!)
    short8 af[4], bf[4];
#pragma unroll
    for (int mi = 0; mi < 4; ++mi)
      af[mi] = *(const short8*)(As + (wm * 64 + mi * 16 + lo) * 32 + quad * 8);
#pragma unroll
    for (int ni = 0; ni < 4; ++ni)
      bf[ni] = *(const short8*)(Bs + (wn * 64 + ni * 16 + lo) * 32 + quad * 8);
#pragma unroll
    for (int mi = 0; mi < 4; ++mi)
#pragma unroll
      for (int ni = 0; ni < 4; ++ni)
        acc[mi][ni] = __builtin_amdgcn_mfma_f32_16x16x32_bf16(af[mi], bf[ni], acc[mi][ni], 0, 0, 0);
    __syncthreads();  // LDS reads done before next stage
  }

  const float* bihp = (dk < 4) ? bihf : bihb;
  const float* bhhp = (dk < 4) ? bhhf : bhhb;
#pragma unroll
  for (int ni = 0; ni < 4; ++ni) {
    int g = ntl * 128 + wn * 64 + ni * 16 + lo;
    float bv = bihp[kh * 2048 + g] + bhhp[kh * 2048 + g];
#pragma unroll
    for (int mi = 0; mi < 4; ++mi)
#pragma unroll
      for (int r = 0; r < 4; ++r) {
        int m = mt * 128 + wm * 64 + mi * 16 + quad * 4 + r;
        ih[((size_t)dk * 1024 + m) * 2048 + g] = acc[mi][ni][r] + bv;
      }
  }
}

// Persistent recurrence (R5 structure). grid=128: grp = bid&7, wg = bid>>3
// owns h-cols [wg*32, +32). Wave w = gate, 2 N-tiles each.
// stateS[grp][s][8][128] ull: slot s = h input for step s; poison-polled.
// R10: LDS_BARRIER (no vmcnt drain) instead of __syncthreads.
__global__ __launch_bounds__(256) void lstm_rec_k(
    const float* __restrict__ ih, const unsigned short* __restrict__ whh,
    float* __restrict__ out, ull* __restrict__ stateS) {
  const int tid = threadIdx.x;
  const int L = tid & 63;
  const int w = tid >> 6;
  const int grp = blockIdx.x & 7;
  const int d = grp >> 2, kh = grp & 3;
  const int wg = blockIdx.x >> 3;
  const int j0 = wg * 32;
  const int quad = L >> 4, lo = L & 15;

  __shared__ unsigned short h_lds[16 * 520];  // rows 8..15 stay zero (M-pad)
  __shared__ float gbuf[4][8][32];            // [gate][b][jj]

  for (int i = tid; i < 16 * 520; i += 256) h_lds[i] = 0;

  // Whh slice -> B-frags (resident; R8 proved no per-step reloads)
  short8 bfrag[2][16];
#pragma unroll
  for (int ni = 0; ni < 2; ++ni) {
    const unsigned short* wb =
        whh + ((size_t)grp * 2048 + (size_t)(w * 512 + j0 + ni * 16 + lo)) * 512 + quad * 8;
#pragma unroll
    for (int kk = 0; kk < 16; ++kk) bfrag[ni][kk] = *(const short8*)(wb + kk * 32);
  }

  const int pb = tid >> 5, pjj = tid & 31;  // pointwise cell (b, jj)
  float creg = 0.0f;

  // prefetch ih gates for s=0 (bias already folded by GEMM)
  float ihv[2][4];
  {
    int t0 = d ? 127 : 0;
#pragma unroll
    for (int ni = 0; ni < 2; ++ni) {
      const float* ihp =
          ih + ((size_t)grp * 1024 + (size_t)t0 * 8) * 2048 + (w * 512 + j0 + ni * 16 + lo);
#pragma unroll
      for (int r = 0; r < 4; ++r) {
        int b = quad * 4 + r;
        ihv[ni][r] = (b < 8) ? ihp[(size_t)b * 2048] : 0.0f;
      }
    }
  }

  const int srow = tid >> 5;         // batch row 0..7
  const int scol = (tid & 31) * 16;  // h-col base within row (elements)

  for (int s = 0; s < 128; ++s) {
    const int t = d ? (127 - s) : s;

    if (s) {  // stage h_prev: poll slot s until this thread's producers wrote it
      const ull* src = stateS + ((size_t)grp * 128 + s) * 1024 + tid * 4;
      ull v0, v1, v2, v3;
      do {
        v0 = __hip_atomic_load(src + 0, __ATOMIC_RELAXED, __HIP_MEMORY_SCOPE_AGENT);
        v1 = __hip_atomic_load(src + 1, __ATOMIC_RELAXED, __HIP_MEMORY_SCOPE_AGENT);
        v2 = __hip_atomic_load(src + 2, __ATOMIC_RELAXED, __HIP_MEMORY_SCOPE_AGENT);
        v3 = __hip_atomic_load(src + 3, __ATOMIC_RELAXED, __HIP_MEMORY_SCOPE_AGENT);
      } while (v0 == POISON || v1 == POISON || v2 == POISON || v3 == POISON);
      unsigned short* dl = h_lds + srow * 520 + scol;
      *(ull*)(dl + 0) = v0;
      *(ull*)(dl + 4) = v1;
      *(ull*)(dl + 8) = v2;
      *(ull*)(dl + 12) = v3;
    }
    LDS_BARRIER();  // h_lds staged; NO vmcnt drain (stores fire-and-forget)

    floatx4 acc[2] = {};
    floatx4 acc2[2] = {};
    {  // A[m][k]: m = L&15 (batch, rows 8..15 zero); 2 independent chains
      const unsigned short* ar = h_lds + lo * 520 + quad * 8;
#pragma unroll
      for (int kk = 0; kk < 16; kk += 2) {
        short8 a0 = *(const short8*)(ar + kk * 32);
        short8 a1 = *(const short8*)(ar + (kk + 1) * 32);
#pragma unroll
        for (int ni = 0; ni < 2; ++ni) {
          acc[ni]  = __builtin_amdgcn_mfma_f32_16x16x32_bf16(a0, bfrag[ni][kk], acc[ni], 0, 0, 0);
          acc2[ni] = __builtin_amdgcn_mfma_f32_16x16x32_bf16(a1, bfrag[ni][kk + 1], acc2[ni], 0, 0, 0);
        }
      }
    }
#pragma unroll
    for (int ni = 0; ni < 2; ++ni)
#pragma unroll
      for (int r = 0; r < 4; ++r) {
        int b = quad * 4 + r;
        if (b < 8) gbuf[w][b][ni * 16 + lo] = acc[ni][r] + acc2[ni][r] + ihv[ni][r];
      }

    if (s < 127) {  // prefetch ih for s+1 (in flight across the barrier now)
      int tn = d ? (126 - s) : (s + 1);
#pragma unroll
      for (int ni = 0; ni < 2; ++ni) {
        const float* ihp =
            ih + ((size_t)grp * 1024 + (size_t)tn * 8) * 2048 + (w * 512 + j0 + ni * 16 + lo);
#pragma unroll
        for (int r = 0; r < 4; ++r) {
          int b = quad * 4 + r;
          ihv[ni][r] = (b < 8) ? ihp[(size_t)b * 2048] : 0.0f;
        }
      }
    }
    LDS_BARRIER();  // gbuf visible; ih prefetch NOT drained here (key win)

    // pointwise LSTM cell: one (b, jj) per thread
    {
      float ig = gbuf[0][pb][pjj], fg = gbuf[1][pb][pjj];
      float gg = gbuf[2][pb][pjj], og = gbuf[3][pb][pjj];
      float cn = sigm(fg) * creg + sigm(ig) * tanh_f(gg);
      creg = cn;
      float h = sigm(og) * tanh_f(cn);

      if (s < 127) {  // publish h into slot s+1: shfl-pack 4 lanes -> 8B store
        unsigned hs = f2bf(h);
        int base = L & ~3;
        unsigned v0 = __shfl(hs, base + 0);
        unsigned v1 = __shfl(hs, base + 1);
        unsigned v2 = __shfl(hs, base + 2);
        unsigned v3 = __shfl(hs, base + 3);
        if ((L & 3) == 0) {
          ull wv = (ull)v0 | ((ull)v1 << 16) | ((ull)v2 << 32) | ((ull)v3 << 48);
          ull* dst = stateS + ((size_t)grp * 128 + (s + 1)) * 1024 + pb * 128 + ((j0 + pjj) >> 2);
          __hip_atomic_store(dst, wv, __ATOMIC_RELAXED, __HIP_MEMORY_SCOPE_AGENT);
        }
      }
      out[(((size_t)pb * 128 + t) * 1024 + d * 512 + j0 + pjj) * 4 + kh] = h;
    }
  }
}

extern "C" void kernel_launch(void* const* d_in, const int* in_sizes, int n_in,
                              void* d_out, int out_size, void* d_ws, size_t ws_size,
                              hipStream_t stream) {
  (void)in_sizes; (void)n_in; (void)out_size; (void)ws_size;
  const float* x     = (const float*)d_in[0];
  const float* Wih_f = (const float*)d_in[1];
  const float* Whh_f = (const float*)d_in[2];
  const float* bih_f = (const float*)d_in[3];
  const float* bhh_f = (const float*)d_in[4];
  const float* Wih_b = (const float*)d_in[5];
  const float* Whh_b = (const float*)d_in[6];
  const float* bih_b = (const float*)d_in[7];
  const float* bhh_b = (const float*)d_in[8];
  float* out = (float*)d_out;
  char* ws = (char*)d_ws;

  ull* stateS          = (ull*)ws;                               // 8 MB
  float* ihg           = (float*)(ws + (8ull << 20));            // 64 MB
  unsigned short* Xp   = (unsigned short*)(ws + (72ull << 20));  // 8 MB
  unsigned short* Wihb = (unsigned short*)(ws + (80ull << 20));  // 32 MB
  unsigned short* Whhb = (unsigned short*)(ws + (112ull << 20)); // 16 MB

  prep_k<<<32768, 256, 0, stream>>>(x, Wih_f, Wih_b, Whh_f, Whh_b, Xp, Wihb, Whhb, stateS);
  gemm_ih_k<<<1024, 256, 0, stream>>>(Xp, Wihb, bih_f, bhh_f, bih_b, bhh_b, ihg);
  lstm_rec_k<<<128, 256, 0, stream>>>(ihg, Whhb, out, stateS);
}

// Round 7
// 418.911 us; speedup vs baseline: 1.3966x; 1.0989x over previous
//
#include <hip/hip_runtime.h>
#include <stdint.h>

// Multi_LSTMs: bidirectional 4-head LSTM, BS=8 NT=128 CH=1024 H=512 G=2048.
// R1-R4: poison-poll state exchange, no fences in step loop.
// R5: recurrence MFMA accumulation split into 2 independent chains.
// R6 FAILED: GEMM/recurrence fusion. R7 FAILED: 5-change bundle.
// R8 REFUTED residency theory. R9 REFUTED spin-traffic theory.
// R10: LDS_BARRIER (no vmcnt drain) -12us. Residual found: the poll's own
//   compare needs vmcnt(0) (FIFO waitcnt semantics) -> it drains the late-
//   issued ih HBM prefetch + store acks every step. The drain MOVED, not died.
// R11 (this round): issue the ih prefetch for step s+1 at the LOOP TOP of
//   step s, BEFORE the poll. Inside this step's poll the ~900cy load drain
//   hides under the >=1200cy publish-visibility wait (poll can't succeed
//   earlier); by the next poll the loads retired long ago. Consumption stays
//   one step later (ihv <- ihvN at loop bottom) so the use-wait is counted
//   and already satisfied. Single lever; GEMM/prep untouched.

typedef __attribute__((ext_vector_type(8))) short short8;
typedef __attribute__((ext_vector_type(4))) float floatx4;
typedef unsigned long long ull;

#define POISON 0x7FC07FC07FC07FC0ull  // 4 x bf16 NaN (stateS)

// Barrier WITHOUT the implicit vmcnt(0) drain: only LDS ops must be visible.
#define LDS_BARRIER()                                       \
  do {                                                      \
    asm volatile("s_waitcnt lgkmcnt(0)" ::: "memory");      \
    __builtin_amdgcn_s_barrier();                           \
  } while (0)

#define GLOAD_LDS16(g, l)                                        \
  __builtin_amdgcn_global_load_lds(                              \
      (const __attribute__((address_space(1))) void*)(g),        \
      (__attribute__((address_space(3))) void*)(l), 16, 0, 0)

__device__ __forceinline__ unsigned short f2bf(float f) {
  unsigned u = __float_as_uint(f);
  u = (u + 0x7fffu + ((u >> 16) & 1u)) >> 16;  // RNE
  return (unsigned short)u;
}
__device__ __forceinline__ float sigm(float x) { return 1.0f / (1.0f + __expf(-x)); }
__device__ __forceinline__ float tanh_f(float x) {
  float ax = fabsf(x);
  float e = __expf(-2.0f * ax);
  float t = (1.0f - e) / (1.0f + e);
  return x < 0.0f ? -t : t;
}

// One prep kernel: pack x, cast Wih_f/Wih_b/Whh_f/Whh_b to bf16, poison stateS.
__global__ __launch_bounds__(256) void prep_k(
    const float* __restrict__ x,
    const float* __restrict__ Wih_f, const float* __restrict__ Wih_b,
    const float* __restrict__ Whh_f, const float* __restrict__ Whh_b,
    unsigned short* __restrict__ Xp, unsigned short* __restrict__ Wihb,
    unsigned short* __restrict__ Whhb, ull* __restrict__ stateS) {
  size_t i = (size_t)blockIdx.x * 256 + threadIdx.x;
  if (i < 1048576) {  // pack x: x[8][128][1024][4] f32 -> Xp[4][1024][1024] bf16
    int g = (int)i;
    int m = g >> 10, c = g & 1023;
    int t = m >> 3, b = m & 7;
    float4 v = *(const float4*)(x + ((size_t)((b * 128 + t) * 1024 + c)) * 4);
    Xp[g]           = f2bf(v.x);
    Xp[1048576 + g] = f2bf(v.y);
    Xp[2097152 + g] = f2bf(v.z);
    Xp[3145728 + g] = f2bf(v.w);
  } else if (i < 3145728) {  // Wih_f: 2M float4
    size_t j = i - 1048576;
    float4 v = ((const float4*)Wih_f)[j];
    ushort4 o;
    o.x = f2bf(v.x); o.y = f2bf(v.y); o.z = f2bf(v.z); o.w = f2bf(v.w);
    ((ushort4*)Wihb)[j] = o;
  } else if (i < 5242880) {  // Wih_b
    size_t j = i - 3145728;
    float4 v = ((const float4*)Wih_b)[j];
    ushort4 o;
    o.x = f2bf(v.x); o.y = f2bf(v.y); o.z = f2bf(v.z); o.w = f2bf(v.w);
    ((ushort4*)Wihb)[2097152 + j] = o;
  } else if (i < 6291456) {  // Whh_f: 1M float4
    size_t j = i - 5242880;
    float4 v = ((const float4*)Whh_f)[j];
    ushort4 o;
    o.x = f2bf(v.x); o.y = f2bf(v.y); o.z = f2bf(v.z); o.w = f2bf(v.w);
    ((ushort4*)Whhb)[j] = o;
  } else if (i < 7340032) {  // Whh_b
    size_t j = i - 6291456;
    float4 v = ((const float4*)Whh_b)[j];
    ushort4 o;
    o.x = f2bf(v.x); o.y = f2bf(v.y); o.z = f2bf(v.z); o.w = f2bf(v.w);
    ((ushort4*)Whhb)[1048576 + j] = o;
  } else {  // stateS poison: 1M ull
    stateS[i - 7340032] = POISON;
  }
}

// ih[dk][m][g] = sum_c Xp[kh][m][c] * Wb[dk][g][c] + bih[g] + bhh[g]
// m97 structure: 128x128 tile, BK=32, global_load_lds(16B), 4 waves 2x2.
// XCD-panel swizzle (R9, ~neutral but kept): panel p=(dk,ntl) pinned to XCD p&7.
__global__ __launch_bounds__(256) void gemm_ih_k(
    const unsigned short* __restrict__ Xp, const unsigned short* __restrict__ Wb,
    const float* __restrict__ bihf, const float* __restrict__ bhhf,
    const float* __restrict__ bihb, const float* __restrict__ bhhb,
    float* __restrict__ ih) {
  const int bid = blockIdx.x;
  const int xcd = bid & 7;
  const int q   = bid >> 3;    // 0..127
  const int mt  = q & 7;
  const int p   = (q >> 3) * 8 + xcd;  // panel 0..127
  const int dk  = p >> 4;
  const int ntl = p & 15;
  const int kh = dk & 3;
  const int tid = threadIdx.x;
  const int L = tid & 63, w = tid >> 6;
  const int wm = w & 1, wn = w >> 1;
  const int quad = L >> 4, lo = L & 15;

  __shared__ unsigned short As[128 * 32];  // 8 KB, no pad (glds contiguity)
  __shared__ unsigned short Bs[128 * 32];

  const unsigned short* Ab = Xp + (size_t)kh * 1048576 + (size_t)mt * 128 * 1024;
  const unsigned short* Bb = Wb + (size_t)dk * 2097152 + (size_t)ntl * 128 * 1024;

  floatx4 acc[4][4] = {};

  for (int kc = 0; kc < 32; ++kc) {
#pragma unroll
    for (int ph = 0; ph < 2; ++ph) {
      int c = ph * 256 + w * 64 + L;       // 16B chunk id, 0..511
      int ldsb = (ph * 256 + w * 64) * 8;  // wave-uniform base (shorts)
      GLOAD_LDS16(Ab + (size_t)(c >> 2) * 1024 + kc * 32 + (c & 3) * 8, As + ldsb);
      GLOAD_LDS16(Bb + (size_t)(c >> 2) * 1024 + kc * 32 + (c & 3) * 8, Bs + ldsb);
    }
    __syncthreads();  // implicit vmcnt(0): LDS tiles ready (needed here!)
    short8 af[4], bf[4];
#pragma unroll
    for (int mi = 0; mi < 4; ++mi)
      af[mi] = *(const short8*)(As + (wm * 64 + mi * 16 + lo) * 32 + quad * 8);
#pragma unroll
    for (int ni = 0; ni < 4; ++ni)
      bf[ni] = *(const short8*)(Bs + (wn * 64 + ni * 16 + lo) * 32 + quad * 8);
#pragma unroll
    for (int mi = 0; mi < 4; ++mi)
#pragma unroll
      for (int ni = 0; ni < 4; ++ni)
        acc[mi][ni] = __builtin_amdgcn_mfma_f32_16x16x32_bf16(af[mi], bf[ni], acc[mi][ni], 0, 0, 0);
    __syncthreads();  // LDS reads done before next stage
  }

  const float* bihp = (dk < 4) ? bihf : bihb;
  const float* bhhp = (dk < 4) ? bhhf : bhhb;
#pragma unroll
  for (int ni = 0; ni < 4; ++ni) {
    int g = ntl * 128 + wn * 64 + ni * 16 + lo;
    float bv = bihp[kh * 2048 + g] + bhhp[kh * 2048 + g];
#pragma unroll
    for (int mi = 0; mi < 4; ++mi)
#pragma unroll
      for (int r = 0; r < 4; ++r) {
        int m = mt * 128 + wm * 64 + mi * 16 + quad * 4 + r;
        ih[((size_t)dk * 1024 + m) * 2048 + g] = acc[mi][ni][r] + bv;
      }
  }
}

// Persistent recurrence (R5 structure + R10 LDS_BARRIER + R11 loop-top
// prefetch). grid=128: grp = bid&7, wg = bid>>3 owns h-cols [wg*32, +32).
// Wave w = gate, 2 N-tiles each. stateS slot s poison-polled.
__global__ __launch_bounds__(256) void lstm_rec_k(
    const float* __restrict__ ih, const unsigned short* __restrict__ whh,
    float* __restrict__ out, ull* __restrict__ stateS) {
  const int tid = threadIdx.x;
  const int L = tid & 63;
  const int w = tid >> 6;
  const int grp = blockIdx.x & 7;
  const int d = grp >> 2, kh = grp & 3;
  const int wg = blockIdx.x >> 3;
  const int j0 = wg * 32;
  const int quad = L >> 4, lo = L & 15;

  __shared__ unsigned short h_lds[16 * 520];  // rows 8..15 stay zero (M-pad)
  __shared__ float gbuf[4][8][32];            // [gate][b][jj]

  for (int i = tid; i < 16 * 520; i += 256) h_lds[i] = 0;

  // Whh slice -> B-frags (resident; R8 proved no per-step reloads)
  short8 bfrag[2][16];
#pragma unroll
  for (int ni = 0; ni < 2; ++ni) {
    const unsigned short* wb =
        whh + ((size_t)grp * 2048 + (size_t)(w * 512 + j0 + ni * 16 + lo)) * 512 + quad * 8;
#pragma unroll
    for (int kk = 0; kk < 16; ++kk) bfrag[ni][kk] = *(const short8*)(wb + kk * 32);
  }

  const int pb = tid >> 5, pjj = tid & 31;  // pointwise cell (b, jj)
  float creg = 0.0f;

  // prefetch ih gates for s=0 (bias already folded by GEMM)
  float ihv[2][4];
  {
    int t0 = d ? 127 : 0;
#pragma unroll
    for (int ni = 0; ni < 2; ++ni) {
      const float* ihp =
          ih + ((size_t)grp * 1024 + (size_t)t0 * 8) * 2048 + (w * 512 + j0 + ni * 16 + lo);
#pragma unroll
      for (int r = 0; r < 4; ++r) {
        int b = quad * 4 + r;
        ihv[ni][r] = (b < 8) ? ihp[(size_t)b * 2048] : 0.0f;
      }
    }
  }

  const int srow = tid >> 5;         // batch row 0..7
  const int scol = (tid & 31) * 16;  // h-col base within row (elements)

  for (int s = 0; s < 128; ++s) {
    const int t = d ? (127 - s) : s;

    // R11: issue ih prefetch for s+1 FIRST, before the poll. Its ~900cy HBM
    // latency hides under this poll's publish-visibility wait, and it is
    // fully retired before the NEXT poll's vmcnt(0).
    float ihvN[2][4];
    if (s < 127) {
      int tn = d ? (126 - s) : (s + 1);
#pragma unroll
      for (int ni = 0; ni < 2; ++ni) {
        const float* ihp =
            ih + ((size_t)grp * 1024 + (size_t)tn * 8) * 2048 + (w * 512 + j0 + ni * 16 + lo);
#pragma unroll
        for (int r = 0; r < 4; ++r) {
          int b = quad * 4 + r;
          ihvN[ni][r] = (b < 8) ? ihp[(size_t)b * 2048] : 0.0f;
        }
      }
    } else {
#pragma unroll
      for (int ni = 0; ni < 2; ++ni)
#pragma unroll
        for (int r = 0; r < 4; ++r) ihvN[ni][r] = 0.0f;
    }

    if (s) {  // stage h_prev: poll slot s until this thread's producers wrote it
      const ull* src = stateS + ((size_t)grp * 128 + s) * 1024 + tid * 4;
      ull v0, v1, v2, v3;
      do {
        v0 = __hip_atomic_load(src + 0, __ATOMIC_RELAXED, __HIP_MEMORY_SCOPE_AGENT);
        v1 = __hip_atomic_load(src + 1, __ATOMIC_RELAXED, __HIP_MEMORY_SCOPE_AGENT);
        v2 = __hip_atomic_load(src + 2, __ATOMIC_RELAXED, __HIP_MEMORY_SCOPE_AGENT);
        v3 = __hip_atomic_load(src + 3, __ATOMIC_RELAXED, __HIP_MEMORY_SCOPE_AGENT);
      } while (v0 == POISON || v1 == POISON || v2 == POISON || v3 == POISON);
      unsigned short* dl = h_lds + srow * 520 + scol;
      *(ull*)(dl + 0) = v0;
      *(ull*)(dl + 4) = v1;
      *(ull*)(dl + 8) = v2;
      *(ull*)(dl + 12) = v3;
    }
    LDS_BARRIER();  // h_lds staged; NO vmcnt drain

    floatx4 acc[2] = {};
    floatx4 acc2[2] = {};
    {  // A[m][k]: m = L&15 (batch, rows 8..15 zero); 2 independent chains
      const unsigned short* ar = h_lds + lo * 520 + quad * 8;
#pragma unroll
      for (int kk = 0; kk < 16; kk += 2) {
        short8 a0 = *(const short8*)(ar + kk * 32);
        short8 a1 = *(const short8*)(ar + (kk + 1) * 32);
#pragma unroll
        for (int ni = 0; ni < 2; ++ni) {
          acc[ni]  = __builtin_amdgcn_mfma_f32_16x16x32_bf16(a0, bfrag[ni][kk], acc[ni], 0, 0, 0);
          acc2[ni] = __builtin_amdgcn_mfma_f32_16x16x32_bf16(a1, bfrag[ni][kk + 1], acc2[ni], 0, 0, 0);
        }
      }
    }
#pragma unroll
    for (int ni = 0; ni < 2; ++ni)
#pragma unroll
      for (int r = 0; r < 4; ++r) {
        int b = quad * 4 + r;
        if (b < 8) gbuf[w][b][ni * 16 + lo] = acc[ni][r] + acc2[ni][r] + ihv[ni][r];
      }
    LDS_BARRIER();  // gbuf visible; in-flight prefetch NOT drained

    // pointwise LSTM cell: one (b, jj) per thread
    {
      float ig = gbuf[0][pb][pjj], fg = gbuf[1][pb][pjj];
      float gg = gbuf[2][pb][pjj], og = gbuf[3][pb][pjj];
      float cn = sigm(fg) * creg + sigm(ig) * tanh_f(gg);
      creg = cn;
      float h = sigm(og) * tanh_f(cn);

      if (s < 127) {  // publish h into slot s+1: shfl-pack 4 lanes -> 8B store
        unsigned hs = f2bf(h);
        int base = L & ~3;
        unsigned v0 = __shfl(hs, base + 0);
        unsigned v1 = __shfl(hs, base + 1);
        unsigned v2 = __shfl(hs, base + 2);
        unsigned v3 = __shfl(hs, base + 3);
        if ((L & 3) == 0) {
          ull wv = (ull)v0 | ((ull)v1 << 16) | ((ull)v2 << 32) | ((ull)v3 << 48);
          ull* dst = stateS + ((size_t)grp * 128 + (s + 1)) * 1024 + pb * 128 + ((j0 + pjj) >> 2);
          __hip_atomic_store(dst, wv, __ATOMIC_RELAXED, __HIP_MEMORY_SCOPE_AGENT);
        }
      }
      out[(((size_t)pb * 128 + t) * 1024 + d * 512 + j0 + pjj) * 4 + kh] = h;
    }

#pragma unroll
    for (int ni = 0; ni < 2; ++ni)
#pragma unroll
      for (int r = 0; r < 4; ++r) ihv[ni][r] = ihvN[ni][r];
  }
}

extern "C" void kernel_launch(void* const* d_in, const int* in_sizes, int n_in,
                              void* d_out, int out_size, void* d_ws, size_t ws_size,
                              hipStream_t stream) {
  (void)in_sizes; (void)n_in; (void)out_size; (void)ws_size;
  const float* x     = (const float*)d_in[0];
  const float* Wih_f = (const float*)d_in[1];
  const float* Whh_f = (const float*)d_in[2];
  const float* bih_f = (const float*)d_in[3];
  const float* bhh_f = (const float*)d_in[4];
  const float* Wih_b = (const float*)d_in[5];
  const float* Whh_b = (const float*)d_in[6];
  const float* bih_b = (const float*)d_in[7];
  const float* bhh_b = (const float*)d_in[8];
  float* out = (float*)d_out;
  char* ws = (char*)d_ws;

  ull* stateS          = (ull*)ws;                               // 8 MB
  float* ihg           = (float*)(ws + (8ull << 20));            // 64 MB
  unsigned short* Xp   = (unsigned short*)(ws + (72ull << 20));  // 8 MB
  unsigned short* Wihb = (unsigned short*)(ws + (80ull << 20));  // 32 MB
  unsigned short* Whhb = (unsigned short*)(ws + (112ull << 20)); // 16 MB

  prep_k<<<32768, 256, 0, stream>>>(x, Wih_f, Wih_b, Whh_f, Whh_b, Xp, Wihb, Whhb, stateS);
  gemm_ih_k<<<1024, 256, 0, stream>>>(Xp, Wihb, bih_f, bhh_f, bih_b, bhh_b, ihg);
  lstm_rec_k<<<128, 256, 0, stream>>>(ihg, Whhb, out, stateS);
}